// Round 6
// baseline (407.455 us; speedup 1.0000x reference)
//
#include <hip/hip_runtime.h>

#define N_NODES 50000
#define E_EDGES 800000
#define NEG_SLOPE 0.2f
#define NSL 8
#define SLN (NSL * N_NODES)          // 400000
#define NB1 196                      // ceil(N/256)
#define NB2 1563                     // ceil(8N/256)
#define ROWS_PAD 50048               // N padded to 64-row multiple for GEMM A-tiles

typedef __attribute__((ext_vector_type(8))) short bf16x8;
typedef __attribute__((ext_vector_type(4))) float f32x4;
typedef __attribute__((ext_vector_type(4))) _Float16 half4v;

// truncate-split: f ~= hi + lo with |err| <= 2^-16 |f|
__device__ __forceinline__ void split_bf(float f, unsigned short& h, unsigned short& l) {
    unsigned u = __float_as_uint(f);
    h = (unsigned short)(u >> 16);
    float r = f - __uint_as_float((unsigned)h << 16);
    l = (unsigned short)(__float_as_uint(r) >> 16);
}

__device__ __forceinline__ float lrelu(float t) { return (t > 0.f) ? t : NEG_SLOPE * t; }

// async global->LDS DMA, 16B per lane; LDS dest = wave-uniform base + lane*16
__device__ __forceinline__ void gload_lds16(const void* g, void* l) {
    __builtin_amdgcn_global_load_lds((__attribute__((address_space(1))) void*)g,
                                     (__attribute__((address_space(3))) void*)l, 16, 0, 0);
}

// ---------------- input split kernels ----------------

__global__ void k_split4(const float* __restrict__ in, unsigned short* __restrict__ H,
                         unsigned short* __restrict__ L, int n4) {
    int i = blockIdx.x * blockDim.x + threadIdx.x;
    if (i >= n4) return;
    float4 v = ((const float4*)in)[i];
    ushort4 h, l;
    split_bf(v.x, h.x, l.x);
    split_bf(v.y, h.y, l.y);
    split_bf(v.z, h.z, l.z);
    split_bf(v.w, h.w, l.w);
    ((ushort4*)H)[i] = h;
    ((ushort4*)L)[i] = l;
}

// W[Kd][Nc] f32 -> Ht,Lt [Nc][Kd] bf16 (transposed)
__global__ void k_split_wt(const float* __restrict__ W, unsigned short* __restrict__ Ht,
                           unsigned short* __restrict__ Lt, int Kd, int Nc) {
    int i = blockIdx.x * blockDim.x + threadIdx.x;
    if (i >= Kd * Nc) return;
    int k = i / Nc, c = i % Nc;
    unsigned short h, l;
    split_bf(W[i], h, l);
    Ht[c * Kd + k] = h;
    Lt[c * Kd + k] = l;
}

// ---------------- CSR build: slice-local scatter + regroup ----------------

__global__ void k_hist(const int* __restrict__ dst0, const int* __restrict__ dst1,
                       int* __restrict__ deg_s) {
    const int layer = blockIdx.y;
    const int slice = blockIdx.x & (NSL - 1);
    int i = blockIdx.x * blockDim.x + threadIdx.x;
    if (i >= E_EDGES) return;
    int d = (layer == 0) ? dst0[i] : dst1[i];
    atomicAdd(&deg_s[layer * SLN + slice * N_NODES + d], 1);
}

__global__ void k_scan1A(const int* __restrict__ deg_s, int* __restrict__ rowptr,
                         int* __restrict__ bsum) {
    const int layer = blockIdx.y;
    __shared__ int lds[256];
    int t = threadIdx.x;
    int i = blockIdx.x * 256 + t;
    int v = 0;
    if (i < N_NODES) {
        const int* d = deg_s + layer * SLN + i;
#pragma unroll
        for (int s = 0; s < NSL; ++s) v += d[s * N_NODES];
    }
    lds[t] = v;
    __syncthreads();
    for (int off = 1; off < 256; off <<= 1) {
        int u = (t >= off) ? lds[t - off] : 0;
        __syncthreads();
        lds[t] += u;
        __syncthreads();
    }
    if (i < N_NODES) rowptr[layer * (N_NODES + 1) + i + 1] = lds[t];
    if (t == 255) bsum[layer * 256 + blockIdx.x] = lds[255];
}

__global__ void k_scanB(const int* __restrict__ bsum, int* __restrict__ boff, int nb) {
    const int layer = blockIdx.x;
    const int* bs = bsum + layer * 256;
    int* bo = boff + layer * 256;
    __shared__ int lds[256];
    int t = threadIdx.x;
    int v = (t < nb) ? bs[t] : 0;
    lds[t] = v;
    __syncthreads();
    for (int off = 1; off < 256; off <<= 1) {
        int u = (t >= off) ? lds[t - off] : 0;
        __syncthreads();
        lds[t] += u;
        __syncthreads();
    }
    if (t < nb) bo[t] = lds[t] - v;
}

__global__ void k_scan1C(const int* __restrict__ boff, int* __restrict__ rowptr) {
    const int layer = blockIdx.y;
    int i = blockIdx.x * blockDim.x + threadIdx.x;
    if (i >= N_NODES) return;
    int* rp = rowptr + layer * (N_NODES + 1);
    rp[i + 1] += boff[layer * 256 + (i >> 8)];
    if (i == 0) rp[0] = 0;
}

__global__ void k_scan2A(const int* __restrict__ deg_s, int* __restrict__ rowptr_s,
                         int* __restrict__ bsum2) {
    const int layer = blockIdx.y;
    __shared__ int lds[256];
    int t = threadIdx.x;
    int i = blockIdx.x * 256 + t;
    int v = (i < SLN) ? deg_s[layer * SLN + i] : 0;
    lds[t] = v;
    __syncthreads();
    for (int off = 1; off < 256; off <<= 1) {
        int u = (t >= off) ? lds[t - off] : 0;
        __syncthreads();
        lds[t] += u;
        __syncthreads();
    }
    if (i < SLN) rowptr_s[layer * SLN + i] = lds[t];
    if (t == 255) bsum2[layer * NB2 + blockIdx.x] = lds[255];
}

__global__ void k_scan2B(const int* __restrict__ bsum2, int* __restrict__ boff2) {
    const int layer = blockIdx.x;
    __shared__ int lds[256];
    __shared__ int carry;
    int t = threadIdx.x;
    if (t == 0) carry = 0;
    __syncthreads();
    for (int c = 0; c < NB2; c += 256) {
        int v = (c + t < NB2) ? bsum2[layer * NB2 + c + t] : 0;
        lds[t] = v;
        __syncthreads();
        for (int off = 1; off < 256; off <<= 1) {
            int u = (t >= off) ? lds[t - off] : 0;
            __syncthreads();
            lds[t] += u;
            __syncthreads();
        }
        if (c + t < NB2) boff2[layer * NB2 + c + t] = carry + lds[t] - v;
        __syncthreads();
        if (t == 255) carry += lds[255];
        __syncthreads();
    }
}

__global__ void k_scan2C(const int* __restrict__ deg_s, const int* __restrict__ boff2,
                         int* __restrict__ rowptr_s, int* __restrict__ cursor_s) {
    const int layer = blockIdx.y;
    int i = blockIdx.x * 256 + threadIdx.x;
    if (i >= SLN) return;
    const int base = layer * SLN;
    int b = rowptr_s[base + i] + boff2[layer * NB2 + (i >> 8)] - deg_s[base + i];
    rowptr_s[base + i] = b;
    cursor_s[base + i] = b;
}

__global__ void k_scatter(const int* __restrict__ src0, const int* __restrict__ dst0,
                          const int* __restrict__ src1, const int* __restrict__ dst1,
                          int* __restrict__ cursor_s, int* __restrict__ tmp) {
    const int layer = blockIdx.y;
    const int slice = blockIdx.x & (NSL - 1);
    int i = blockIdx.x * blockDim.x + threadIdx.x;
    if (i >= E_EDGES) return;
    int s, d;
    if (layer == 0) { s = src0[i]; d = dst0[i]; }
    else            { s = src1[i]; d = dst1[i]; }
    int pos = atomicAdd(&cursor_s[layer * SLN + slice * N_NODES + d], 1);
    tmp[layer * E_EDGES + pos] = s;
}

__global__ __launch_bounds__(256) void k_regroup(const int* __restrict__ deg_s,
                                                 const int* __restrict__ rowptr_s,
                                                 const int* __restrict__ rowptr,
                                                 const int* __restrict__ tmp,
                                                 int* __restrict__ csr) {
    const int layer = blockIdx.y;
    const int lane = threadIdx.x & 63;
    const int node = blockIdx.x * 4 + (threadIdx.x >> 6);
    if (node >= N_NODES) return;
    const int base = layer * SLN;
    int dg = 0, tb = 0;
    if (lane < NSL) {
        dg = deg_s[base + lane * N_NODES + node];
        tb = rowptr_s[base + lane * N_NODES + node];
    }
    int excl = 0, total = 0;
#pragma unroll
    for (int ss = 0; ss < NSL; ++ss) {
        int v = __shfl(dg, ss);
        if (ss < (lane & 7)) excl += v;
        total += v;
    }
    const int base_out = rowptr[layer * (N_NODES + 1) + node];
    const int* tsrc = tmp + (size_t)layer * E_EDGES;
    int* cdst = csr + (size_t)layer * E_EDGES;
    for (int r0 = 0; r0 < total; r0 += 64) {
        int r = r0 + lane;
        bool active = (r < total);
        int rr = active ? r : 0;
        int s = 0;
#pragma unroll
        for (int ss = 1; ss < NSL; ++ss) {
            int e = __shfl(excl, ss);
            if (rr >= e) s = ss;
        }
        int eS  = __shfl(excl, s);
        int tbS = __shfl(tb, s);
        if (active) cdst[base_out + r] = tsrc[tbS + (r - eS)];
    }
}

// ---------------- split-bf16 MFMA GEMM v2 ----------------
// C[M,BN](fp16) = A[M,256]*B[256,BN], A/B pre-split into bf16 H/L tables,
// B pre-transposed [BN][256]. BM=64, 4 waves (wave w owns all 64 rows x cols
// [w*BN/4, +BN/4)). LDS layout [kblk][row][8]: each fragment = 16 contiguous B,
// staged via global_load_lds (lane-consecutive 16B slots -> conflict-free).

template<int BN>
__global__ __launch_bounds__(256, 4) void mfma_gemm2(const unsigned short* __restrict__ AH,
                                                     const unsigned short* __restrict__ AL,
                                                     const unsigned short* __restrict__ BHt,
                                                     const unsigned short* __restrict__ BLt,
                                                     _Float16* __restrict__ C, int M) {
    constexpr int K = 256;
    constexpr int BK = 32;
    constexpr int CT = BN / 64;   // 16-col tiles per wave
    constexpr int WC = BN / 4;    // cols per wave
    __shared__ __align__(16) unsigned short AsH[4 * 64 * 8];
    __shared__ __align__(16) unsigned short AsL[4 * 64 * 8];
    __shared__ __align__(16) unsigned short BsH[4 * BN * 8];
    __shared__ __align__(16) unsigned short BsL[4 * BN * 8];

    const int t = threadIdx.x;
    const int w = t >> 6;
    const int lane = t & 63;
    const int r16 = lane & 15;
    const int kg = lane >> 4;
    const int bm = blockIdx.x * 64;

    f32x4 acc[4][CT];
#pragma unroll
    for (int i = 0; i < 4; ++i)
#pragma unroll
        for (int j = 0; j < CT; ++j) acc[i][j] = (f32x4){0.f, 0.f, 0.f, 0.f};

    // A staging: lane loads 16B of row (bm+lane) at k-block w -> slot w*64+lane
    const unsigned short* agH = AH + (size_t)(bm + lane) * K + w * 8;
    const unsigned short* agL = AL + (size_t)(bm + lane) * K + w * 8;
    unsigned short* aldH = &AsH[w * 512];
    unsigned short* aldL = &AsL[w * 512];

    for (int k0 = 0; k0 < K; k0 += BK) {
        gload_lds16(agH + k0, aldH);
        gload_lds16(agL + k0, aldL);
#pragma unroll
        for (int p = 0; p < BN / 64; ++p) {
            int slot = p * 256 + t;
            int c = slot / BN;
            int col = slot % BN;
            int sbase = (slot - lane) * 8;   // wave-uniform
            const size_t goff = (size_t)col * K + k0 + c * 8;
            gload_lds16(BHt + goff, &BsH[sbase]);
            gload_lds16(BLt + goff, &BsL[sbase]);
        }
        __syncthreads();

        bf16x8 aH[4], aL[4];
#pragma unroll
        for (int rt = 0; rt < 4; ++rt) {
            aH[rt] = *(const bf16x8*)&AsH[(kg * 64 + rt * 16 + r16) * 8];
            aL[rt] = *(const bf16x8*)&AsL[(kg * 64 + rt * 16 + r16) * 8];
        }
#pragma unroll
        for (int ct = 0; ct < CT; ++ct) {
            const int cb = (kg * BN + w * WC + ct * 16 + r16) * 8;
            const bf16x8 bH = *(const bf16x8*)&BsH[cb];
            const bf16x8 bL = *(const bf16x8*)&BsL[cb];
#pragma unroll
            for (int rt = 0; rt < 4; ++rt) {
                acc[rt][ct] = __builtin_amdgcn_mfma_f32_16x16x32_bf16(aH[rt], bH, acc[rt][ct], 0, 0, 0);
                acc[rt][ct] = __builtin_amdgcn_mfma_f32_16x16x32_bf16(aH[rt], bL, acc[rt][ct], 0, 0, 0);
                acc[rt][ct] = __builtin_amdgcn_mfma_f32_16x16x32_bf16(aL[rt], bH, acc[rt][ct], 0, 0, 0);
            }
        }
        __syncthreads();
    }

#pragma unroll
    for (int rt = 0; rt < 4; ++rt) {
#pragma unroll
        for (int r = 0; r < 4; ++r) {
            int row = bm + rt * 16 + kg * 4 + r;
            if (row < M) {
#pragma unroll
                for (int ct = 0; ct < CT; ++ct)
                    C[(size_t)row * BN + w * WC + ct * 16 + r16] = (_Float16)acc[rt][ct][r];
            }
        }
    }
}

// ---------------- layer 0 edge kernel: fp16 gathers, 4-edge unroll ----------------
// Epilogue writes h0 as split bf16 H/L tables (feeds GEMM1 directly).

__global__ __launch_bounds__(256) void gat_edge0(const _Float16* __restrict__ feat,
                                                 const float* __restrict__ attn,
                                                 const int* __restrict__ rowptr,
                                                 const int* __restrict__ csr,
                                                 unsigned short* __restrict__ h0H,
                                                 unsigned short* __restrict__ h0L) {
    const int lane = threadIdx.x & 63;
    const int node = blockIdx.x * 4 + (threadIdx.x >> 6);
    if (node >= N_NODES) return;
    const int dbase = ((lane >> 4) << 6) + (lane & 15) * 4;
    const float4 a = *(const float4*)&attn[dbase];
    const half4v fdh = *(const half4v*)&feat[(size_t)node * 256 + dbase];
    const float fdx = (float)fdh[0], fdy = (float)fdh[1], fdz = (float)fdh[2], fdw = (float)fdh[3];
    const int beg = rowptr[node], end = rowptr[node + 1];
    float m = -1e30f, s = 0.f;
    float ax = 0.f, ay = 0.f, az = 0.f, aw = 0.f;
    int j = beg;
    for (; j + 3 < end; j += 4) {
        int sn0 = csr[j], sn1 = csr[j + 1], sn2 = csr[j + 2], sn3 = csr[j + 3];
        half4v h0 = *(const half4v*)&feat[(size_t)sn0 * 256 + dbase];
        half4v h1 = *(const half4v*)&feat[(size_t)sn1 * 256 + dbase];
        half4v h2 = *(const half4v*)&feat[(size_t)sn2 * 256 + dbase];
        half4v h3 = *(const half4v*)&feat[(size_t)sn3 * 256 + dbase];
        float f0x = (float)h0[0], f0y = (float)h0[1], f0z = (float)h0[2], f0w = (float)h0[3];
        float f1x = (float)h1[0], f1y = (float)h1[1], f1z = (float)h1[2], f1w = (float)h1[3];
        float f2x = (float)h2[0], f2y = (float)h2[1], f2z = (float)h2[2], f2w = (float)h2[3];
        float f3x = (float)h3[0], f3y = (float)h3[1], f3z = (float)h3[2], f3w = (float)h3[3];
        float p0 = lrelu(f0x + fdx) * a.x + lrelu(f0y + fdy) * a.y + lrelu(f0z + fdz) * a.z + lrelu(f0w + fdw) * a.w;
        float p1 = lrelu(f1x + fdx) * a.x + lrelu(f1y + fdy) * a.y + lrelu(f1z + fdz) * a.z + lrelu(f1w + fdw) * a.w;
        float p2 = lrelu(f2x + fdx) * a.x + lrelu(f2y + fdy) * a.y + lrelu(f2z + fdz) * a.z + lrelu(f2w + fdw) * a.w;
        float p3 = lrelu(f3x + fdx) * a.x + lrelu(f3y + fdy) * a.y + lrelu(f3z + fdz) * a.z + lrelu(f3w + fdw) * a.w;
        p0 += __shfl_xor(p0, 1); p1 += __shfl_xor(p1, 1); p2 += __shfl_xor(p2, 1); p3 += __shfl_xor(p3, 1);
        p0 += __shfl_xor(p0, 2); p1 += __shfl_xor(p1, 2); p2 += __shfl_xor(p2, 2); p3 += __shfl_xor(p3, 2);
        p0 += __shfl_xor(p0, 4); p1 += __shfl_xor(p1, 4); p2 += __shfl_xor(p2, 4); p3 += __shfl_xor(p3, 4);
        p0 += __shfl_xor(p0, 8); p1 += __shfl_xor(p1, 8); p2 += __shfl_xor(p2, 8); p3 += __shfl_xor(p3, 8);
        float nm = fmaxf(fmaxf(m, fmaxf(p0, p1)), fmaxf(p2, p3));
        float c  = __expf(m - nm);
        float e0 = __expf(p0 - nm);
        float e1 = __expf(p1 - nm);
        float e2 = __expf(p2 - nm);
        float e3 = __expf(p3 - nm);
        s  = s  * c + e0 + e1 + e2 + e3;
        ax = ax * c + e0 * f0x + e1 * f1x + e2 * f2x + e3 * f3x;
        ay = ay * c + e0 * f0y + e1 * f1y + e2 * f2y + e3 * f3y;
        az = az * c + e0 * f0z + e1 * f1z + e2 * f2z + e3 * f3z;
        aw = aw * c + e0 * f0w + e1 * f1w + e2 * f2w + e3 * f3w;
        m = nm;
    }
    for (; j < end; ++j) {
        int sn = csr[j];
        half4v hv = *(const half4v*)&feat[(size_t)sn * 256 + dbase];
        float fx = (float)hv[0], fy = (float)hv[1], fz = (float)hv[2], fw = (float)hv[3];
        float p = lrelu(fx + fdx) * a.x + lrelu(fy + fdy) * a.y + lrelu(fz + fdz) * a.z + lrelu(fw + fdw) * a.w;
        p += __shfl_xor(p, 1);
        p += __shfl_xor(p, 2);
        p += __shfl_xor(p, 4);
        p += __shfl_xor(p, 8);
        float nm = fmaxf(m, p);
        float c  = __expf(m - nm);
        float e  = __expf(p - nm);
        s  = s  * c + e;
        ax = ax * c + e * fx;
        ay = ay * c + e * fy;
        az = az * c + e * fz;
        aw = aw * c + e * fw;
        m = nm;
    }
    float inv = (end > beg) ? (1.0f / s) : 0.f;
    ushort4 oh, ol;
    float v;
    v = ax * inv; v = (v > 0.f) ? v : (__expf(v) - 1.f); split_bf(v, oh.x, ol.x);
    v = ay * inv; v = (v > 0.f) ? v : (__expf(v) - 1.f); split_bf(v, oh.y, ol.y);
    v = az * inv; v = (v > 0.f) ? v : (__expf(v) - 1.f); split_bf(v, oh.z, ol.z);
    v = aw * inv; v = (v > 0.f) ? v : (__expf(v) - 1.f); split_bf(v, oh.w, ol.w);
    *(ushort4*)&h0H[(size_t)node * 256 + dbase] = oh;
    *(ushort4*)&h0L[(size_t)node * 256 + dbase] = ol;
}

// ---------------- layer 1 edge kernel: 4 edges in flight ----------------

__global__ __launch_bounds__(256) void gat_edge1(const _Float16* __restrict__ feat,
                                                 const float* __restrict__ attn,
                                                 const int* __restrict__ rowptr,
                                                 const int* __restrict__ csr,
                                                 float* __restrict__ out) {
    const int lane = threadIdx.x & 63;
    const int node = blockIdx.x * 4 + (threadIdx.x >> 6);
    if (node >= N_NODES) return;
    const int g = lane >> 4;
    const int d0 = (lane & 15) * 4;
    const float4 a = *(const float4*)&attn[d0];
    const half4v fdh = *(const half4v*)&feat[(size_t)node * 64 + d0];
    const float fdx = (float)fdh[0], fdy = (float)fdh[1], fdz = (float)fdh[2], fdw = (float)fdh[3];
    const int beg = rowptr[node], end = rowptr[node + 1];
    float m = -1e30f, s = 0.f;
    float ax = 0.f, ay = 0.f, az = 0.f, aw = 0.f;
    for (int j = beg + g; j < end; j += 4) {
        int sn = csr[j];
        half4v hv = *(const half4v*)&feat[(size_t)sn * 64 + d0];
        float fx = (float)hv[0], fy = (float)hv[1], fz = (float)hv[2], fw = (float)hv[3];
        float p = lrelu(fx + fdx) * a.x + lrelu(fy + fdy) * a.y + lrelu(fz + fdz) * a.z + lrelu(fw + fdw) * a.w;
        p += __shfl_xor(p, 1);
        p += __shfl_xor(p, 2);
        p += __shfl_xor(p, 4);
        p += __shfl_xor(p, 8);
        float nm = fmaxf(m, p);
        float c  = __expf(m - nm);
        float e  = __expf(p - nm);
        s  = s  * c + e;
        ax = ax * c + e * fx;
        ay = ay * c + e * fy;
        az = az * c + e * fz;
        aw = aw * c + e * fw;
        m = nm;
    }
#pragma unroll
    for (int off = 16; off <= 32; off <<= 1) {
        float mo = __shfl_xor(m, off);
        float so = __shfl_xor(s, off);
        float bx = __shfl_xor(ax, off);
        float by = __shfl_xor(ay, off);
        float bz = __shfl_xor(az, off);
        float bw = __shfl_xor(aw, off);
        float nm = fmaxf(m, mo);
        float c  = __expf(m - nm);
        float co = __expf(mo - nm);
        s  = s  * c + so * co;
        ax = ax * c + bx * co;
        ay = ay * c + by * co;
        az = az * c + bz * co;
        aw = aw * c + bw * co;
        m = nm;
    }
    if (g == 0) {
        float inv = (end > beg) ? (1.0f / s) : 0.f;
        float4 o = make_float4(ax * inv, ay * inv, az * inv, aw * inv);
        *(float4*)&out[(size_t)node * 64 + d0] = o;
    }
}

// ---------------- launch ----------------

extern "C" void kernel_launch(void* const* d_in, const int* in_sizes, int n_in,
                              void* d_out, int out_size, void* d_ws, size_t ws_size,
                              hipStream_t stream) {
    const float* x     = (const float*)d_in[0];
    const float* W0    = (const float*)d_in[1];
    const float* attn0 = (const float*)d_in[2];
    const float* W1    = (const float*)d_in[3];
    const float* attn1 = (const float*)d_in[4];
    const int*   src0  = (const int*)d_in[5];
    const int*   dst0  = (const int*)d_in[6];
    const int*   src1  = (const int*)d_in[7];
    const int*   dst1  = (const int*)d_in[8];
    float* out = (float*)d_out;

    unsigned short* xH = (unsigned short*)d_ws;                // ROWS_PAD*256 (alias h0H)
    unsigned short* xL = xH + (size_t)ROWS_PAD * 256;          // ROWS_PAD*256 (alias h0L)
    _Float16* feat0h = (_Float16*)(xL + (size_t)ROWS_PAD * 256); // N*256 fp16 (alias feat1h)
    unsigned short* W0Ht = (unsigned short*)(feat0h + (size_t)N_NODES * 256);
    unsigned short* W0Lt = W0Ht + 256 * 256;
    unsigned short* W1Ht = W0Lt + 256 * 256;
    unsigned short* W1Lt = W1Ht + 64 * 256;
    unsigned short* h0H = xH;
    unsigned short* h0L = xL;
    _Float16* feat1h = feat0h;

    int* deg_s    = (int*)(W1Lt + 64 * 256);
    int* rowptr   = deg_s + 2 * SLN;
    int* rowptr_s = rowptr + 2 * (N_NODES + 1);
    int* cursor_s = rowptr_s + 2 * SLN;
    int* bsum1    = cursor_s + 2 * SLN;
    int* boff1    = bsum1 + 512;
    int* bsum2    = boff1 + 512;
    int* boff2    = bsum2 + 2 * NB2;
    int* tmp      = boff2 + 2 * NB2;
    int* csr      = tmp + 2 * E_EDGES;

    const int eb  = E_EDGES / 256;                 // 3125
    const int nb2 = (SLN + 255) / 256;             // 1563
    const int gb  = (N_NODES + 63) / 64;           // 782

    // ---- input splits ----
    k_split4  <<<(N_NODES * 256 / 4 + 255) / 256, 256, 0, stream>>>(x, xH, xL, N_NODES * 64);
    k_split_wt<<<(256 * 256 + 255) / 256, 256, 0, stream>>>(W0, W0Ht, W0Lt, 256, 256);
    k_split_wt<<<(256 * 64 + 255) / 256, 256, 0, stream>>>(W1, W1Ht, W1Lt, 256, 64);

    // ---- CSR build (both layers) ----
    hipMemsetAsync(deg_s, 0, 2 * SLN * sizeof(int), stream);
    k_hist  <<<dim3(eb, 2),  256, 0, stream>>>(dst0, dst1, deg_s);
    k_scan1A<<<dim3(NB1, 2), 256, 0, stream>>>(deg_s, rowptr, bsum1);
    k_scanB <<<2,            256, 0, stream>>>(bsum1, boff1, NB1);
    k_scan1C<<<dim3(NB1, 2), 256, 0, stream>>>(boff1, rowptr);
    k_scan2A<<<dim3(nb2, 2), 256, 0, stream>>>(deg_s, rowptr_s, bsum2);
    k_scan2B<<<2,            256, 0, stream>>>(bsum2, boff2);
    k_scan2C<<<dim3(nb2, 2), 256, 0, stream>>>(deg_s, boff2, rowptr_s, cursor_s);
    k_scatter<<<dim3(eb, 2), 256, 0, stream>>>(src0, dst0, src1, dst1, cursor_s, tmp);
    k_regroup<<<dim3((N_NODES + 3) / 4, 2), 256, 0, stream>>>(deg_s, rowptr_s, rowptr, tmp, csr);

    // ---- layer 0 ----
    mfma_gemm2<256><<<gb, 256, 0, stream>>>(xH, xL, W0Ht, W0Lt, feat0h, N_NODES);
    gat_edge0<<<(N_NODES + 3) / 4, 256, 0, stream>>>(feat0h, attn0, rowptr, csr, h0H, h0L);

    // ---- layer 1 ----
    mfma_gemm2<64><<<gb, 256, 0, stream>>>(h0H, h0L, W1Ht, W1Lt, feat1h, N_NODES);
    gat_edge1<<<(N_NODES + 3) / 4, 256, 0, stream>>>(feat1h, attn1,
                                                     rowptr + (N_NODES + 1), csr + E_EDGES, out);
}

// Round 7
// 349.573 us; speedup vs baseline: 1.1656x; 1.1656x over previous
//
#include <hip/hip_runtime.h>

#define N_NODES 50000
#define E_EDGES 800000
#define NEG_SLOPE 0.2f
#define NSL 8
#define SLN (NSL * N_NODES)          // 400000
#define NB1 196                      // ceil(N/256)
#define NB2 1563                     // ceil(8N/256)
#define ROWS_PAD 50048               // N padded to 64

typedef __attribute__((ext_vector_type(8))) short bf16x8;
typedef __attribute__((ext_vector_type(4))) float f32x4;
typedef __attribute__((ext_vector_type(4))) _Float16 half4v;

// truncate-split: f ~= hi + lo with |err| <= 2^-16 |f|
__device__ __forceinline__ void split_bf(float f, unsigned short& h, unsigned short& l) {
    unsigned u = __float_as_uint(f);
    h = (unsigned short)(u >> 16);
    float r = f - __uint_as_float((unsigned)h << 16);
    l = (unsigned short)(__float_as_uint(r) >> 16);
}

__device__ __forceinline__ unsigned short rne_bf(float f) {
    unsigned u = __float_as_uint(f);
    unsigned r = u + 0x7FFF + ((u >> 16) & 1);
    return (unsigned short)(r >> 16);
}

__device__ __forceinline__ float lrelu(float t) { return (t > 0.f) ? t : NEG_SLOPE * t; }

// async global->LDS DMA, 16B/lane; LDS dest = wave-uniform base + lane*16
__device__ __forceinline__ void gload_lds16(const void* g, void* l) {
    __builtin_amdgcn_global_load_lds((__attribute__((address_space(1))) void*)g,
                                     (__attribute__((address_space(3))) void*)l, 16, 0, 0);
}

// ---------------- image builders ----------------
// Fragment image: elem (row,k) -> img[((row/16)*8 + k/32)*512 + ((row&15) + ((k>>3)&3)*16)*8 + (k&7)]

__global__ void k_aimg(const float* __restrict__ x, unsigned short* __restrict__ AH,
                       unsigned short* __restrict__ AL) {
    int i = blockIdx.x * blockDim.x + threadIdx.x;      // (row, chunk8)
    if (i >= N_NODES * 32) return;
    int row = i >> 5, chunk = i & 31;
    float4 v0 = *(const float4*)&x[(size_t)row * 256 + chunk * 8];
    float4 v1 = *(const float4*)&x[(size_t)row * 256 + chunk * 8 + 4];
    ushort4 h0, h1, l0, l1;
    split_bf(v0.x, h0.x, l0.x); split_bf(v0.y, h0.y, l0.y);
    split_bf(v0.z, h0.z, l0.z); split_bf(v0.w, h0.w, l0.w);
    split_bf(v1.x, h1.x, l1.x); split_bf(v1.y, h1.y, l1.y);
    split_bf(v1.z, h1.z, l1.z); split_bf(v1.w, h1.w, l1.w);
    int rtg = row >> 4, kb = chunk >> 2;
    int li = (row & 15) + (chunk & 3) * 16;
    size_t base = ((size_t)rtg * 8 + kb) * 512 + li * 8;
    *(ushort4*)&AH[base] = h0; *(ushort4*)&AH[base + 4] = h1;
    *(ushort4*)&AL[base] = l0; *(ushort4*)&AL[base + 4] = l1;
}

// W[k][Nc] f32 -> bf16 (RNE) fragment image over [k=256][Nc cols]
__global__ void k_wimg(const float* __restrict__ W, unsigned short* __restrict__ img, int Nc) {
    int i = blockIdx.x * blockDim.x + threadIdx.x;      // (col, chunk8)
    if (i >= Nc * 32) return;
    int col = i >> 5, chunk = i & 31;
    int CT = Nc >> 4;
    int kb = chunk >> 2, ct = col >> 4;
    int li = (col & 15) + (chunk & 3) * 16;
    size_t base = ((size_t)kb * CT + ct) * 512 + li * 8;
    unsigned short v[8];
#pragma unroll
    for (int e = 0; e < 8; ++e) v[e] = rne_bf(W[(size_t)(chunk * 8 + e) * Nc + col]);
    *(ushort4*)&img[base]     = make_ushort4(v[0], v[1], v[2], v[3]);
    *(ushort4*)&img[base + 4] = make_ushort4(v[4], v[5], v[6], v[7]);
}

// ---------------- CSR build: slice-local scatter + regroup ----------------

__global__ void k_hist(const int* __restrict__ dst0, const int* __restrict__ dst1,
                       int* __restrict__ deg_s) {
    const int layer = blockIdx.y;
    const int slice = blockIdx.x & (NSL - 1);
    int i = blockIdx.x * blockDim.x + threadIdx.x;
    if (i >= E_EDGES) return;
    int d = (layer == 0) ? dst0[i] : dst1[i];
    atomicAdd(&deg_s[layer * SLN + slice * N_NODES + d], 1);
}

__global__ void k_scan1A(const int* __restrict__ deg_s, int* __restrict__ rowptr,
                         int* __restrict__ bsum) {
    const int layer = blockIdx.y;
    __shared__ int lds[256];
    int t = threadIdx.x;
    int i = blockIdx.x * 256 + t;
    int v = 0;
    if (i < N_NODES) {
        const int* d = deg_s + layer * SLN + i;
#pragma unroll
        for (int s = 0; s < NSL; ++s) v += d[s * N_NODES];
    }
    lds[t] = v;
    __syncthreads();
    for (int off = 1; off < 256; off <<= 1) {
        int u = (t >= off) ? lds[t - off] : 0;
        __syncthreads();
        lds[t] += u;
        __syncthreads();
    }
    if (i < N_NODES) rowptr[layer * (N_NODES + 1) + i + 1] = lds[t];
    if (t == 255) bsum[layer * 256 + blockIdx.x] = lds[255];
}

__global__ void k_scanB(const int* __restrict__ bsum, int* __restrict__ boff, int nb) {
    const int layer = blockIdx.x;
    const int* bs = bsum + layer * 256;
    int* bo = boff + layer * 256;
    __shared__ int lds[256];
    int t = threadIdx.x;
    int v = (t < nb) ? bs[t] : 0;
    lds[t] = v;
    __syncthreads();
    for (int off = 1; off < 256; off <<= 1) {
        int u = (t >= off) ? lds[t - off] : 0;
        __syncthreads();
        lds[t] += u;
        __syncthreads();
    }
    if (t < nb) bo[t] = lds[t] - v;
}

__global__ void k_scan1C(const int* __restrict__ boff, int* __restrict__ rowptr) {
    const int layer = blockIdx.y;
    int i = blockIdx.x * blockDim.x + threadIdx.x;
    if (i >= N_NODES) return;
    int* rp = rowptr + layer * (N_NODES + 1);
    rp[i + 1] += boff[layer * 256 + (i >> 8)];
    if (i == 0) rp[0] = 0;
}

__global__ void k_scan2A(const int* __restrict__ deg_s, int* __restrict__ rowptr_s,
                         int* __restrict__ bsum2) {
    const int layer = blockIdx.y;
    __shared__ int lds[256];
    int t = threadIdx.x;
    int i = blockIdx.x * 256 + t;
    int v = (i < SLN) ? deg_s[layer * SLN + i] : 0;
    lds[t] = v;
    __syncthreads();
    for (int off = 1; off < 256; off <<= 1) {
        int u = (t >= off) ? lds[t - off] : 0;
        __syncthreads();
        lds[t] += u;
        __syncthreads();
    }
    if (i < SLN) rowptr_s[layer * SLN + i] = lds[t];
    if (t == 255) bsum2[layer * NB2 + blockIdx.x] = lds[255];
}

__global__ void k_scan2B(const int* __restrict__ bsum2, int* __restrict__ boff2) {
    const int layer = blockIdx.x;
    __shared__ int lds[256];
    __shared__ int carry;
    int t = threadIdx.x;
    if (t == 0) carry = 0;
    __syncthreads();
    for (int c = 0; c < NB2; c += 256) {
        int v = (c + t < NB2) ? bsum2[layer * NB2 + c + t] : 0;
        lds[t] = v;
        __syncthreads();
        for (int off = 1; off < 256; off <<= 1) {
            int u = (t >= off) ? lds[t - off] : 0;
            __syncthreads();
            lds[t] += u;
            __syncthreads();
        }
        if (c + t < NB2) boff2[layer * NB2 + c + t] = carry + lds[t] - v;
        __syncthreads();
        if (t == 255) carry += lds[255];
        __syncthreads();
    }
}

__global__ void k_scan2C(const int* __restrict__ deg_s, const int* __restrict__ boff2,
                         int* __restrict__ rowptr_s, int* __restrict__ cursor_s) {
    const int layer = blockIdx.y;
    int i = blockIdx.x * 256 + threadIdx.x;
    if (i >= SLN) return;
    const int base = layer * SLN;
    int b = rowptr_s[base + i] + boff2[layer * NB2 + (i >> 8)] - deg_s[base + i];
    rowptr_s[base + i] = b;
    cursor_s[base + i] = b;
}

__global__ void k_scatter(const int* __restrict__ src0, const int* __restrict__ dst0,
                          const int* __restrict__ src1, const int* __restrict__ dst1,
                          int* __restrict__ cursor_s, int* __restrict__ tmp) {
    const int layer = blockIdx.y;
    const int slice = blockIdx.x & (NSL - 1);
    int i = blockIdx.x * blockDim.x + threadIdx.x;
    if (i >= E_EDGES) return;
    int s, d;
    if (layer == 0) { s = src0[i]; d = dst0[i]; }
    else            { s = src1[i]; d = dst1[i]; }
    int pos = atomicAdd(&cursor_s[layer * SLN + slice * N_NODES + d], 1);
    tmp[layer * E_EDGES + pos] = s;
}

__global__ __launch_bounds__(256) void k_regroup(const int* __restrict__ deg_s,
                                                 const int* __restrict__ rowptr_s,
                                                 const int* __restrict__ rowptr,
                                                 const int* __restrict__ tmp,
                                                 int* __restrict__ csr) {
    const int layer = blockIdx.y;
    const int lane = threadIdx.x & 63;
    const int node = blockIdx.x * 4 + (threadIdx.x >> 6);
    if (node >= N_NODES) return;
    const int base = layer * SLN;
    int dg = 0, tb = 0;
    if (lane < NSL) {
        dg = deg_s[base + lane * N_NODES + node];
        tb = rowptr_s[base + lane * N_NODES + node];
    }
    int excl = 0, total = 0;
#pragma unroll
    for (int ss = 0; ss < NSL; ++ss) {
        int v = __shfl(dg, ss);
        if (ss < (lane & 7)) excl += v;
        total += v;
    }
    const int base_out = rowptr[layer * (N_NODES + 1) + node];
    const int* tsrc = tmp + (size_t)layer * E_EDGES;
    int* cdst = csr + (size_t)layer * E_EDGES;
    for (int r0 = 0; r0 < total; r0 += 64) {
        int r = r0 + lane;
        bool active = (r < total);
        int rr = active ? r : 0;
        int s = 0;
#pragma unroll
        for (int ss = 1; ss < NSL; ++ss) {
            int e = __shfl(excl, ss);
            if (rr >= e) s = ss;
        }
        int eS  = __shfl(excl, s);
        int tbS = __shfl(tb, s);
        if (active) cdst[base_out + r] = tsrc[tbS + (r - eS)];
    }
}

// ---------------- fragment-image MFMA GEMM ----------------
// C[M,BN](fp16) = A[M,256] * B[256,BN]; A pre-split H/L images, B bf16 image.
// BM=64, 4 waves; wave w owns rows [w*16, w*16+16), all BN cols.
// Per k-iter: linear DMA of A slab (1KB/table/wave) + B slab (CT KB), 2*CT MFMAs/wave.

template<int BN>
__global__ __launch_bounds__(256, 4) void mfma_gemm3(const unsigned short* __restrict__ AH,
                                                     const unsigned short* __restrict__ AL,
                                                     const unsigned short* __restrict__ Bimg,
                                                     _Float16* __restrict__ C, int M) {
    constexpr int CT = BN / 16;
    __shared__ __align__(16) unsigned short AsH[4 * 512];
    __shared__ __align__(16) unsigned short AsL[4 * 512];
    __shared__ __align__(16) unsigned short Bs[CT * 512];

    const int t = threadIdx.x;
    const int w = t >> 6;
    const int lane = t & 63;
    const int r16 = lane & 15;
    const int kg = lane >> 4;
    const int bm = blockIdx.x * 64;

    f32x4 acc[CT];
#pragma unroll
    for (int j = 0; j < CT; ++j) acc[j] = (f32x4){0.f, 0.f, 0.f, 0.f};

    const size_t abase = ((size_t)(blockIdx.x * 4 + w)) * 8 * 512;  // shorts

    for (int kb = 0; kb < 8; ++kb) {
        gload_lds16(AH + abase + kb * 512 + lane * 8, &AsH[w * 512]);
        gload_lds16(AL + abase + kb * 512 + lane * 8, &AsL[w * 512]);
#pragma unroll
        for (int p = 0; p < CT / 4; ++p)
            gload_lds16(Bimg + kb * CT * 512 + p * 2048 + t * 8, &Bs[p * 2048 + w * 512]);
        __syncthreads();

        const bf16x8 aH = *(const bf16x8*)&AsH[w * 512 + lane * 8];
        const bf16x8 aL = *(const bf16x8*)&AsL[w * 512 + lane * 8];
#pragma unroll
        for (int ct = 0; ct < CT; ++ct) {
            const bf16x8 b = *(const bf16x8*)&Bs[ct * 512 + lane * 8];
            acc[ct] = __builtin_amdgcn_mfma_f32_16x16x32_bf16(aH, b, acc[ct], 0, 0, 0);
            acc[ct] = __builtin_amdgcn_mfma_f32_16x16x32_bf16(aL, b, acc[ct], 0, 0, 0);
        }
        __syncthreads();
    }

#pragma unroll
    for (int r = 0; r < 4; ++r) {
        int row = bm + w * 16 + kg * 4 + r;
        if (row < M) {
#pragma unroll
            for (int ct = 0; ct < CT; ++ct)
                C[(size_t)row * BN + ct * 16 + r16] = (_Float16)acc[ct][r];
        }
    }
}

// ---------------- layer 0 edge kernel: fp16 gathers, 4-edge unroll ----------------
// Epilogue writes h0 as split H/L FRAGMENT IMAGES (direct GEMM1 input).

__global__ __launch_bounds__(256) void gat_edge0(const _Float16* __restrict__ feat,
                                                 const float* __restrict__ attn,
                                                 const int* __restrict__ rowptr,
                                                 const int* __restrict__ csr,
                                                 unsigned short* __restrict__ h0H,
                                                 unsigned short* __restrict__ h0L) {
    const int lane = threadIdx.x & 63;
    const int node = blockIdx.x * 4 + (threadIdx.x >> 6);
    if (node >= N_NODES) return;
    const int dbase = ((lane >> 4) << 6) + (lane & 15) * 4;
    const float4 a = *(const float4*)&attn[dbase];
    const half4v fdh = *(const half4v*)&feat[(size_t)node * 256 + dbase];
    const float fdx = (float)fdh[0], fdy = (float)fdh[1], fdz = (float)fdh[2], fdw = (float)fdh[3];
    const int beg = rowptr[node], end = rowptr[node + 1];
    float m = -1e30f, s = 0.f;
    float ax = 0.f, ay = 0.f, az = 0.f, aw = 0.f;
    int j = beg;
    for (; j + 3 < end; j += 4) {
        int sn0 = csr[j], sn1 = csr[j + 1], sn2 = csr[j + 2], sn3 = csr[j + 3];
        half4v h0 = *(const half4v*)&feat[(size_t)sn0 * 256 + dbase];
        half4v h1 = *(const half4v*)&feat[(size_t)sn1 * 256 + dbase];
        half4v h2 = *(const half4v*)&feat[(size_t)sn2 * 256 + dbase];
        half4v h3 = *(const half4v*)&feat[(size_t)sn3 * 256 + dbase];
        float f0x = (float)h0[0], f0y = (float)h0[1], f0z = (float)h0[2], f0w = (float)h0[3];
        float f1x = (float)h1[0], f1y = (float)h1[1], f1z = (float)h1[2], f1w = (float)h1[3];
        float f2x = (float)h2[0], f2y = (float)h2[1], f2z = (float)h2[2], f2w = (float)h2[3];
        float f3x = (float)h3[0], f3y = (float)h3[1], f3z = (float)h3[2], f3w = (float)h3[3];
        float p0 = lrelu(f0x + fdx) * a.x + lrelu(f0y + fdy) * a.y + lrelu(f0z + fdz) * a.z + lrelu(f0w + fdw) * a.w;
        float p1 = lrelu(f1x + fdx) * a.x + lrelu(f1y + fdy) * a.y + lrelu(f1z + fdz) * a.z + lrelu(f1w + fdw) * a.w;
        float p2 = lrelu(f2x + fdx) * a.x + lrelu(f2y + fdy) * a.y + lrelu(f2z + fdz) * a.z + lrelu(f2w + fdw) * a.w;
        float p3 = lrelu(f3x + fdx) * a.x + lrelu(f3y + fdy) * a.y + lrelu(f3z + fdz) * a.z + lrelu(f3w + fdw) * a.w;
        p0 += __shfl_xor(p0, 1); p1 += __shfl_xor(p1, 1); p2 += __shfl_xor(p2, 1); p3 += __shfl_xor(p3, 1);
        p0 += __shfl_xor(p0, 2); p1 += __shfl_xor(p1, 2); p2 += __shfl_xor(p2, 2); p3 += __shfl_xor(p3, 2);
        p0 += __shfl_xor(p0, 4); p1 += __shfl_xor(p1, 4); p2 += __shfl_xor(p2, 4); p3 += __shfl_xor(p3, 4);
        p0 += __shfl_xor(p0, 8); p1 += __shfl_xor(p1, 8); p2 += __shfl_xor(p2, 8); p3 += __shfl_xor(p3, 8);
        float nm = fmaxf(fmaxf(m, fmaxf(p0, p1)), fmaxf(p2, p3));
        float c  = __expf(m - nm);
        float e0 = __expf(p0 - nm);
        float e1 = __expf(p1 - nm);
        float e2 = __expf(p2 - nm);
        float e3 = __expf(p3 - nm);
        s  = s  * c + e0 + e1 + e2 + e3;
        ax = ax * c + e0 * f0x + e1 * f1x + e2 * f2x + e3 * f3x;
        ay = ay * c + e0 * f0y + e1 * f1y + e2 * f2y + e3 * f3y;
        az = az * c + e0 * f0z + e1 * f1z + e2 * f2z + e3 * f3z;
        aw = aw * c + e0 * f0w + e1 * f1w + e2 * f2w + e3 * f3w;
        m = nm;
    }
    for (; j < end; ++j) {
        int sn = csr[j];
        half4v hv = *(const half4v*)&feat[(size_t)sn * 256 + dbase];
        float fx = (float)hv[0], fy = (float)hv[1], fz = (float)hv[2], fw = (float)hv[3];
        float p = lrelu(fx + fdx) * a.x + lrelu(fy + fdy) * a.y + lrelu(fz + fdz) * a.z + lrelu(fw + fdw) * a.w;
        p += __shfl_xor(p, 1);
        p += __shfl_xor(p, 2);
        p += __shfl_xor(p, 4);
        p += __shfl_xor(p, 8);
        float nm = fmaxf(m, p);
        float c  = __expf(m - nm);
        float e  = __expf(p - nm);
        s  = s  * c + e;
        ax = ax * c + e * fx;
        ay = ay * c + e * fy;
        az = az * c + e * fz;
        aw = aw * c + e * fw;
        m = nm;
    }
    float inv = (end > beg) ? (1.0f / s) : 0.f;
    ushort4 oh, ol;
    float v;
    v = ax * inv; v = (v > 0.f) ? v : (__expf(v) - 1.f); split_bf(v, oh.x, ol.x);
    v = ay * inv; v = (v > 0.f) ? v : (__expf(v) - 1.f); split_bf(v, oh.y, ol.y);
    v = az * inv; v = (v > 0.f) ? v : (__expf(v) - 1.f); split_bf(v, oh.z, ol.z);
    v = aw * inv; v = (v > 0.f) ? v : (__expf(v) - 1.f); split_bf(v, oh.w, ol.w);
    // image index for (row=node, k=dbase..dbase+3)
    const int rtg = node >> 4;
    const int kb = dbase >> 5;
    const int li = (node & 15) + ((dbase >> 3) & 3) * 16;
    const size_t idx = ((size_t)rtg * 8 + kb) * 512 + li * 8 + (dbase & 7);
    *(ushort4*)&h0H[idx] = oh;
    *(ushort4*)&h0L[idx] = ol;
}

// ---------------- layer 1 edge kernel: 4 edges in flight ----------------

__global__ __launch_bounds__(256) void gat_edge1(const _Float16* __restrict__ feat,
                                                 const float* __restrict__ attn,
                                                 const int* __restrict__ rowptr,
                                                 const int* __restrict__ csr,
                                                 float* __restrict__ out) {
    const int lane = threadIdx.x & 63;
    const int node = blockIdx.x * 4 + (threadIdx.x >> 6);
    if (node >= N_NODES) return;
    const int g = lane >> 4;
    const int d0 = (lane & 15) * 4;
    const float4 a = *(const float4*)&attn[d0];
    const half4v fdh = *(const half4v*)&feat[(size_t)node * 64 + d0];
    const float fdx = (float)fdh[0], fdy = (float)fdh[1], fdz = (float)fdh[2], fdw = (float)fdh[3];
    const int beg = rowptr[node], end = rowptr[node + 1];
    float m = -1e30f, s = 0.f;
    float ax = 0.f, ay = 0.f, az = 0.f, aw = 0.f;
    for (int j = beg + g; j < end; j += 4) {
        int sn = csr[j];
        half4v hv = *(const half4v*)&feat[(size_t)sn * 64 + d0];
        float fx = (float)hv[0], fy = (float)hv[1], fz = (float)hv[2], fw = (float)hv[3];
        float p = lrelu(fx + fdx) * a.x + lrelu(fy + fdy) * a.y + lrelu(fz + fdz) * a.z + lrelu(fw + fdw) * a.w;
        p += __shfl_xor(p, 1);
        p += __shfl_xor(p, 2);
        p += __shfl_xor(p, 4);
        p += __shfl_xor(p, 8);
        float nm = fmaxf(m, p);
        float c  = __expf(m - nm);
        float e  = __expf(p - nm);
        s  = s  * c + e;
        ax = ax * c + e * fx;
        ay = ay * c + e * fy;
        az = az * c + e * fz;
        aw = aw * c + e * fw;
        m = nm;
    }
#pragma unroll
    for (int off = 16; off <= 32; off <<= 1) {
        float mo = __shfl_xor(m, off);
        float so = __shfl_xor(s, off);
        float bx = __shfl_xor(ax, off);
        float by = __shfl_xor(ay, off);
        float bz = __shfl_xor(az, off);
        float bw = __shfl_xor(aw, off);
        float nm = fmaxf(m, mo);
        float c  = __expf(m - nm);
        float co = __expf(mo - nm);
        s  = s  * c + so * co;
        ax = ax * c + bx * co;
        ay = ay * c + by * co;
        az = az * c + bz * co;
        aw = aw * c + bw * co;
        m = nm;
    }
    if (g == 0) {
        float inv = (end > beg) ? (1.0f / s) : 0.f;
        float4 o = make_float4(ax * inv, ay * inv, az * inv, aw * inv);
        *(float4*)&out[(size_t)node * 64 + d0] = o;
    }
}

// ---------------- launch ----------------

extern "C" void kernel_launch(void* const* d_in, const int* in_sizes, int n_in,
                              void* d_out, int out_size, void* d_ws, size_t ws_size,
                              hipStream_t stream) {
    const float* x     = (const float*)d_in[0];
    const float* W0    = (const float*)d_in[1];
    const float* attn0 = (const float*)d_in[2];
    const float* W1    = (const float*)d_in[3];
    const float* attn1 = (const float*)d_in[4];
    const int*   src0  = (const int*)d_in[5];
    const int*   dst0  = (const int*)d_in[6];
    const int*   src1  = (const int*)d_in[7];
    const int*   dst1  = (const int*)d_in[8];
    float* out = (float*)d_out;

    unsigned short* AHimg = (unsigned short*)d_ws;               // ROWS_PAD*256 (alias h0H)
    unsigned short* ALimg = AHimg + (size_t)ROWS_PAD * 256;      // ROWS_PAD*256 (alias h0L)
    _Float16* feat0h = (_Float16*)(ALimg + (size_t)ROWS_PAD * 256); // N*256 fp16 (alias feat1h)
    unsigned short* W0img = (unsigned short*)(feat0h + (size_t)N_NODES * 256);
    unsigned short* W1img = W0img + 256 * 256;
    unsigned short* h0H = AHimg;
    unsigned short* h0L = ALimg;
    _Float16* feat1h = feat0h;

    int* deg_s    = (int*)(W1img + 64 * 256);
    int* rowptr   = deg_s + 2 * SLN;
    int* rowptr_s = rowptr + 2 * (N_NODES + 1);
    int* cursor_s = rowptr_s + 2 * SLN;
    int* bsum1    = cursor_s + 2 * SLN;
    int* boff1    = bsum1 + 512;
    int* bsum2    = boff1 + 512;
    int* boff2    = bsum2 + 2 * NB2;
    int* tmp      = boff2 + 2 * NB2;
    int* csr      = tmp + 2 * E_EDGES;

    const int eb  = E_EDGES / 256;                 // 3125
    const int nb2 = (SLN + 255) / 256;             // 1563
    const int gb  = ROWS_PAD / 64;                 // 782

    // ---- image builds ----
    k_aimg<<<(N_NODES * 32 + 255) / 256, 256, 0, stream>>>(x, AHimg, ALimg);
    k_wimg<<<(256 * 32 + 255) / 256, 256, 0, stream>>>(W0, W0img, 256);
    k_wimg<<<(64 * 32 + 255) / 256, 256, 0, stream>>>(W1, W1img, 64);

    // ---- CSR build (both layers) ----
    hipMemsetAsync(deg_s, 0, 2 * SLN * sizeof(int), stream);
    k_hist  <<<dim3(eb, 2),  256, 0, stream>>>(dst0, dst1, deg_s);
    k_scan1A<<<dim3(NB1, 2), 256, 0, stream>>>(deg_s, rowptr, bsum1);
    k_scanB <<<2,            256, 0, stream>>>(bsum1, boff1, NB1);
    k_scan1C<<<dim3(NB1, 2), 256, 0, stream>>>(boff1, rowptr);
    k_scan2A<<<dim3(nb2, 2), 256, 0, stream>>>(deg_s, rowptr_s, bsum2);
    k_scan2B<<<2,            256, 0, stream>>>(bsum2, boff2);
    k_scan2C<<<dim3(nb2, 2), 256, 0, stream>>>(deg_s, boff2, rowptr_s, cursor_s);
    k_scatter<<<dim3(eb, 2), 256, 0, stream>>>(src0, dst0, src1, dst1, cursor_s, tmp);
    k_regroup<<<dim3((N_NODES + 3) / 4, 2), 256, 0, stream>>>(deg_s, rowptr_s, rowptr, tmp, csr);

    // ---- layer 0 ----
    mfma_gemm3<256><<<gb, 256, 0, stream>>>(AHimg, ALimg, W0img, feat0h, N_NODES);
    gat_edge0<<<(N_NODES + 3) / 4, 256, 0, stream>>>(feat0h, attn0, rowptr, csr, h0H, h0L);

    // ---- layer 1 ----
    mfma_gemm3<64><<<gb, 256, 0, stream>>>(h0H, h0L, W1img, feat1h, N_NODES);
    gat_edge1<<<(N_NODES + 3) / 4, 256, 0, stream>>>(feat1h, attn1,
                                                     rowptr + (N_NODES + 1), csr + E_EDGES, out);
}

// Round 8
// 344.180 us; speedup vs baseline: 1.1838x; 1.0157x over previous
//
#include <hip/hip_runtime.h>

#define N_NODES 50000
#define E_EDGES 800000
#define NEG_SLOPE 0.2f
#define NSL 8
#define SLN (NSL * N_NODES)          // 400000
#define NB1 196                      // ceil(N/256)
#define NB2 1563                     // ceil(8N/256)
#define ROWS_PAD 50048               // N padded to 64

typedef __attribute__((ext_vector_type(8))) short bf16x8;
typedef __attribute__((ext_vector_type(4))) float f32x4;
typedef __attribute__((ext_vector_type(4))) _Float16 half4v;
typedef __attribute__((ext_vector_type(2))) _Float16 half2v;

union H4 { half4v h4; half2v h2[2]; unsigned u[2]; };

// truncate-split: f ~= hi + lo with |err| <= 2^-16 |f|
__device__ __forceinline__ void split_bf(float f, unsigned short& h, unsigned short& l) {
    unsigned u = __float_as_uint(f);
    h = (unsigned short)(u >> 16);
    float r = f - __uint_as_float((unsigned)h << 16);
    l = (unsigned short)(__float_as_uint(r) >> 16);
}

__device__ __forceinline__ unsigned short rne_bf(float f) {
    unsigned u = __float_as_uint(f);
    unsigned r = u + 0x7FFF + ((u >> 16) & 1);
    return (unsigned short)(r >> 16);
}

// async global->LDS DMA, 16B/lane; LDS dest = wave-uniform base + lane*16
__device__ __forceinline__ void gload_lds16(const void* g, void* l) {
    __builtin_amdgcn_global_load_lds((__attribute__((address_space(1))) void*)g,
                                     (__attribute__((address_space(3))) void*)l, 16, 0, 0);
}

#define LOG2E 1.4426950408889634f

// packed score: p_log2 = sum_d (0.6*log2e*a_d)*z_d + (0.4*log2e*a_d)*|z_d|
__device__ __forceinline__ float score4(half4v g, half4v fd, const H4& A6, const H4& A4) {
    H4 Z; Z.h4 = g + fd;
    H4 B; B.u[0] = Z.u[0] & 0x7FFF7FFFu; B.u[1] = Z.u[1] & 0x7FFF7FFFu;
    float p = __builtin_amdgcn_fdot2(Z.h2[0], A6.h2[0], 0.0f, false);
    p = __builtin_amdgcn_fdot2(Z.h2[1], A6.h2[1], p, false);
    p = __builtin_amdgcn_fdot2(B.h2[0], A4.h2[0], p, false);
    p = __builtin_amdgcn_fdot2(B.h2[1], A4.h2[1], p, false);
    return p;
}

// ---------------- image builders ----------------
// Fragment image: elem (row,k) -> img[((row/16)*8 + k/32)*512 + ((row&15) + ((k>>3)&3)*16)*8 + (k&7)]

__global__ void k_aimg(const float* __restrict__ x, unsigned short* __restrict__ AH,
                       unsigned short* __restrict__ AL) {
    int i = blockIdx.x * blockDim.x + threadIdx.x;      // (row, chunk8)
    if (i >= N_NODES * 32) return;
    int row = i >> 5, chunk = i & 31;
    float4 v0 = *(const float4*)&x[(size_t)row * 256 + chunk * 8];
    float4 v1 = *(const float4*)&x[(size_t)row * 256 + chunk * 8 + 4];
    ushort4 h0, h1, l0, l1;
    split_bf(v0.x, h0.x, l0.x); split_bf(v0.y, h0.y, l0.y);
    split_bf(v0.z, h0.z, l0.z); split_bf(v0.w, h0.w, l0.w);
    split_bf(v1.x, h1.x, l1.x); split_bf(v1.y, h1.y, l1.y);
    split_bf(v1.z, h1.z, l1.z); split_bf(v1.w, h1.w, l1.w);
    int rtg = row >> 4, kb = chunk >> 2;
    int li = (row & 15) + (chunk & 3) * 16;
    size_t base = ((size_t)rtg * 8 + kb) * 512 + li * 8;
    *(ushort4*)&AH[base] = h0; *(ushort4*)&AH[base + 4] = h1;
    *(ushort4*)&AL[base] = l0; *(ushort4*)&AL[base + 4] = l1;
}

// W[k][Nc] f32 -> bf16 (RNE) fragment image over [k=256][Nc cols]
__global__ void k_wimg(const float* __restrict__ W, unsigned short* __restrict__ img, int Nc) {
    int i = blockIdx.x * blockDim.x + threadIdx.x;      // (col, chunk8)
    if (i >= Nc * 32) return;
    int col = i >> 5, chunk = i & 31;
    int CT = Nc >> 4;
    int kb = chunk >> 2, ct = col >> 4;
    int li = (col & 15) + (chunk & 3) * 16;
    size_t base = ((size_t)kb * CT + ct) * 512 + li * 8;
    unsigned short v[8];
#pragma unroll
    for (int e = 0; e < 8; ++e) v[e] = rne_bf(W[(size_t)(chunk * 8 + e) * Nc + col]);
    *(ushort4*)&img[base]     = make_ushort4(v[0], v[1], v[2], v[3]);
    *(ushort4*)&img[base + 4] = make_ushort4(v[4], v[5], v[6], v[7]);
}

// ---------------- CSR build: slice-local scatter + regroup ----------------

__global__ void k_hist(const int* __restrict__ dst0, const int* __restrict__ dst1,
                       int* __restrict__ deg_s) {
    const int layer = blockIdx.y;
    const int slice = blockIdx.x & (NSL - 1);
    int i = blockIdx.x * blockDim.x + threadIdx.x;
    if (i >= E_EDGES) return;
    int d = (layer == 0) ? dst0[i] : dst1[i];
    atomicAdd(&deg_s[layer * SLN + slice * N_NODES + d], 1);
}

__global__ void k_scan1A(const int* __restrict__ deg_s, int* __restrict__ rowptr,
                         int* __restrict__ bsum) {
    const int layer = blockIdx.y;
    __shared__ int lds[256];
    int t = threadIdx.x;
    int i = blockIdx.x * 256 + t;
    int v = 0;
    if (i < N_NODES) {
        const int* d = deg_s + layer * SLN + i;
#pragma unroll
        for (int s = 0; s < NSL; ++s) v += d[s * N_NODES];
    }
    lds[t] = v;
    __syncthreads();
    for (int off = 1; off < 256; off <<= 1) {
        int u = (t >= off) ? lds[t - off] : 0;
        __syncthreads();
        lds[t] += u;
        __syncthreads();
    }
    if (i < N_NODES) rowptr[layer * (N_NODES + 1) + i + 1] = lds[t];
    if (t == 255) bsum[layer * 256 + blockIdx.x] = lds[255];
}

__global__ void k_scanB(const int* __restrict__ bsum, int* __restrict__ boff, int nb) {
    const int layer = blockIdx.x;
    const int* bs = bsum + layer * 256;
    int* bo = boff + layer * 256;
    __shared__ int lds[256];
    int t = threadIdx.x;
    int v = (t < nb) ? bs[t] : 0;
    lds[t] = v;
    __syncthreads();
    for (int off = 1; off < 256; off <<= 1) {
        int u = (t >= off) ? lds[t - off] : 0;
        __syncthreads();
        lds[t] += u;
        __syncthreads();
    }
    if (t < nb) bo[t] = lds[t] - v;
}

__global__ void k_scan1C(const int* __restrict__ boff, int* __restrict__ rowptr) {
    const int layer = blockIdx.y;
    int i = blockIdx.x * blockDim.x + threadIdx.x;
    if (i >= N_NODES) return;
    int* rp = rowptr + layer * (N_NODES + 1);
    rp[i + 1] += boff[layer * 256 + (i >> 8)];
    if (i == 0) rp[0] = 0;
}

__global__ void k_scan2A(const int* __restrict__ deg_s, int* __restrict__ rowptr_s,
                         int* __restrict__ bsum2) {
    const int layer = blockIdx.y;
    __shared__ int lds[256];
    int t = threadIdx.x;
    int i = blockIdx.x * 256 + t;
    int v = (i < SLN) ? deg_s[layer * SLN + i] : 0;
    lds[t] = v;
    __syncthreads();
    for (int off = 1; off < 256; off <<= 1) {
        int u = (t >= off) ? lds[t - off] : 0;
        __syncthreads();
        lds[t] += u;
        __syncthreads();
    }
    if (i < SLN) rowptr_s[layer * SLN + i] = lds[t];
    if (t == 255) bsum2[layer * NB2 + blockIdx.x] = lds[255];
}

__global__ void k_scan2B(const int* __restrict__ bsum2, int* __restrict__ boff2) {
    const int layer = blockIdx.x;
    __shared__ int lds[256];
    __shared__ int carry;
    int t = threadIdx.x;
    if (t == 0) carry = 0;
    __syncthreads();
    for (int c = 0; c < NB2; c += 256) {
        int v = (c + t < NB2) ? bsum2[layer * NB2 + c + t] : 0;
        lds[t] = v;
        __syncthreads();
        for (int off = 1; off < 256; off <<= 1) {
            int u = (t >= off) ? lds[t - off] : 0;
            __syncthreads();
            lds[t] += u;
            __syncthreads();
        }
        if (c + t < NB2) boff2[layer * NB2 + c + t] = carry + lds[t] - v;
        __syncthreads();
        if (t == 255) carry += lds[255];
        __syncthreads();
    }
}

__global__ void k_scan2C(const int* __restrict__ deg_s, const int* __restrict__ boff2,
                         int* __restrict__ rowptr_s, int* __restrict__ cursor_s) {
    const int layer = blockIdx.y;
    int i = blockIdx.x * 256 + threadIdx.x;
    if (i >= SLN) return;
    const int base = layer * SLN;
    int b = rowptr_s[base + i] + boff2[layer * NB2 + (i >> 8)] - deg_s[base + i];
    rowptr_s[base + i] = b;
    cursor_s[base + i] = b;
}

__global__ void k_scatter(const int* __restrict__ src0, const int* __restrict__ dst0,
                          const int* __restrict__ src1, const int* __restrict__ dst1,
                          int* __restrict__ cursor_s, int* __restrict__ tmp) {
    const int layer = blockIdx.y;
    const int slice = blockIdx.x & (NSL - 1);
    int i = blockIdx.x * blockDim.x + threadIdx.x;
    if (i >= E_EDGES) return;
    int s, d;
    if (layer == 0) { s = src0[i]; d = dst0[i]; }
    else            { s = src1[i]; d = dst1[i]; }
    int pos = atomicAdd(&cursor_s[layer * SLN + slice * N_NODES + d], 1);
    tmp[layer * E_EDGES + pos] = s;
}

// regroup writes csr as BYTE offsets of feature rows: <<9 (512B) layer0, <<7 (128B) layer1
__global__ __launch_bounds__(256) void k_regroup(const int* __restrict__ deg_s,
                                                 const int* __restrict__ rowptr_s,
                                                 const int* __restrict__ rowptr,
                                                 const int* __restrict__ tmp,
                                                 int* __restrict__ csr) {
    const int layer = blockIdx.y;
    const int lane = threadIdx.x & 63;
    const int node = blockIdx.x * 4 + (threadIdx.x >> 6);
    if (node >= N_NODES) return;
    const int base = layer * SLN;
    const int sh = (layer == 0) ? 9 : 7;
    int dg = 0, tb = 0;
    if (lane < NSL) {
        dg = deg_s[base + lane * N_NODES + node];
        tb = rowptr_s[base + lane * N_NODES + node];
    }
    int excl = 0, total = 0;
#pragma unroll
    for (int ss = 0; ss < NSL; ++ss) {
        int v = __shfl(dg, ss);
        if (ss < (lane & 7)) excl += v;
        total += v;
    }
    const int base_out = rowptr[layer * (N_NODES + 1) + node];
    const int* tsrc = tmp + (size_t)layer * E_EDGES;
    int* cdst = csr + (size_t)layer * E_EDGES;
    for (int r0 = 0; r0 < total; r0 += 64) {
        int r = r0 + lane;
        bool active = (r < total);
        int rr = active ? r : 0;
        int s = 0;
#pragma unroll
        for (int ss = 1; ss < NSL; ++ss) {
            int e = __shfl(excl, ss);
            if (rr >= e) s = ss;
        }
        int eS  = __shfl(excl, s);
        int tbS = __shfl(tb, s);
        if (active) cdst[base_out + r] = tsrc[tbS + (r - eS)] << sh;
    }
}

// ---------------- fragment-image MFMA GEMM ----------------

template<int BN>
__global__ __launch_bounds__(256, 4) void mfma_gemm3(const unsigned short* __restrict__ AH,
                                                     const unsigned short* __restrict__ AL,
                                                     const unsigned short* __restrict__ Bimg,
                                                     _Float16* __restrict__ C, int M) {
    constexpr int CT = BN / 16;
    __shared__ __align__(16) unsigned short AsH[4 * 512];
    __shared__ __align__(16) unsigned short AsL[4 * 512];
    __shared__ __align__(16) unsigned short Bs[CT * 512];

    const int t = threadIdx.x;
    const int w = t >> 6;
    const int lane = t & 63;
    const int r16 = lane & 15;
    const int kg = lane >> 4;
    const int bm = blockIdx.x * 64;

    f32x4 acc[CT];
#pragma unroll
    for (int j = 0; j < CT; ++j) acc[j] = (f32x4){0.f, 0.f, 0.f, 0.f};

    const size_t abase = ((size_t)(blockIdx.x * 4 + w)) * 8 * 512;  // shorts

    for (int kb = 0; kb < 8; ++kb) {
        gload_lds16(AH + abase + kb * 512 + lane * 8, &AsH[w * 512]);
        gload_lds16(AL + abase + kb * 512 + lane * 8, &AsL[w * 512]);
#pragma unroll
        for (int p = 0; p < CT / 4; ++p)
            gload_lds16(Bimg + kb * CT * 512 + p * 2048 + t * 8, &Bs[p * 2048 + w * 512]);
        __syncthreads();

        const bf16x8 aH = *(const bf16x8*)&AsH[w * 512 + lane * 8];
        const bf16x8 aL = *(const bf16x8*)&AsL[w * 512 + lane * 8];
#pragma unroll
        for (int ct = 0; ct < CT; ++ct) {
            const bf16x8 b = *(const bf16x8*)&Bs[ct * 512 + lane * 8];
            acc[ct] = __builtin_amdgcn_mfma_f32_16x16x32_bf16(aH, b, acc[ct], 0, 0, 0);
            acc[ct] = __builtin_amdgcn_mfma_f32_16x16x32_bf16(aL, b, acc[ct], 0, 0, 0);
        }
        __syncthreads();
    }

#pragma unroll
    for (int r = 0; r < 4; ++r) {
        int row = bm + w * 16 + kg * 4 + r;
        if (row < M) {
#pragma unroll
            for (int ct = 0; ct < CT; ++ct)
                C[(size_t)row * BN + ct * 16 + r16] = (_Float16)acc[ct][r];
        }
    }
}

// ---------------- layer 0 edge kernel: packed fp16 score, no-max softmax ----------------
// csr holds byte offsets (row<<9). lane = head*16+sub owns 4 dims.

__global__ __launch_bounds__(256) void gat_edge0(const _Float16* __restrict__ feat,
                                                 const float* __restrict__ attn,
                                                 const int* __restrict__ rowptr,
                                                 const int* __restrict__ csr,
                                                 unsigned short* __restrict__ h0H,
                                                 unsigned short* __restrict__ h0L) {
    const int lane = threadIdx.x & 63;
    const int node = blockIdx.x * 4 + (threadIdx.x >> 6);
    if (node >= N_NODES) return;
    const int dbase = ((lane >> 4) << 6) + (lane & 15) * 4;
    const float4 a = *(const float4*)&attn[dbase];
    H4 A6, A4;
    A6.h4 = (half4v){(_Float16)(0.6f * LOG2E * a.x), (_Float16)(0.6f * LOG2E * a.y),
                     (_Float16)(0.6f * LOG2E * a.z), (_Float16)(0.6f * LOG2E * a.w)};
    A4.h4 = (half4v){(_Float16)(0.4f * LOG2E * a.x), (_Float16)(0.4f * LOG2E * a.y),
                     (_Float16)(0.4f * LOG2E * a.z), (_Float16)(0.4f * LOG2E * a.w)};
    const char* fbase = (const char*)feat + dbase * 2;
    const half4v fd4 = *(const half4v*)(fbase + ((size_t)node << 9));
    const int beg = rowptr[node], end = rowptr[node + 1];
    float s = 0.f, ax = 0.f, ay = 0.f, az = 0.f, aw = 0.f;
    int j = beg;
    for (; j + 3 < end; j += 4) {
        int o0 = csr[j], o1 = csr[j + 1], o2 = csr[j + 2], o3 = csr[j + 3];
        half4v g0 = *(const half4v*)(fbase + o0);
        half4v g1 = *(const half4v*)(fbase + o1);
        half4v g2 = *(const half4v*)(fbase + o2);
        half4v g3 = *(const half4v*)(fbase + o3);
        float p0 = score4(g0, fd4, A6, A4);
        float p1 = score4(g1, fd4, A6, A4);
        float p2 = score4(g2, fd4, A6, A4);
        float p3 = score4(g3, fd4, A6, A4);
        p0 += __shfl_xor(p0, 1); p1 += __shfl_xor(p1, 1); p2 += __shfl_xor(p2, 1); p3 += __shfl_xor(p3, 1);
        p0 += __shfl_xor(p0, 2); p1 += __shfl_xor(p1, 2); p2 += __shfl_xor(p2, 2); p3 += __shfl_xor(p3, 2);
        p0 += __shfl_xor(p0, 4); p1 += __shfl_xor(p1, 4); p2 += __shfl_xor(p2, 4); p3 += __shfl_xor(p3, 4);
        p0 += __shfl_xor(p0, 8); p1 += __shfl_xor(p1, 8); p2 += __shfl_xor(p2, 8); p3 += __shfl_xor(p3, 8);
        float e0 = __builtin_amdgcn_exp2f(p0);
        float e1 = __builtin_amdgcn_exp2f(p1);
        float e2 = __builtin_amdgcn_exp2f(p2);
        float e3 = __builtin_amdgcn_exp2f(p3);
        s  += e0 + e1 + e2 + e3;
        ax += e0 * (float)g0[0] + e1 * (float)g1[0] + e2 * (float)g2[0] + e3 * (float)g3[0];
        ay += e0 * (float)g0[1] + e1 * (float)g1[1] + e2 * (float)g2[1] + e3 * (float)g3[1];
        az += e0 * (float)g0[2] + e1 * (float)g1[2] + e2 * (float)g2[2] + e3 * (float)g3[2];
        aw += e0 * (float)g0[3] + e1 * (float)g1[3] + e2 * (float)g2[3] + e3 * (float)g3[3];
    }
    for (; j < end; ++j) {
        half4v g0 = *(const half4v*)(fbase + csr[j]);
        float p0 = score4(g0, fd4, A6, A4);
        p0 += __shfl_xor(p0, 1);
        p0 += __shfl_xor(p0, 2);
        p0 += __shfl_xor(p0, 4);
        p0 += __shfl_xor(p0, 8);
        float e0 = __builtin_amdgcn_exp2f(p0);
        s  += e0;
        ax += e0 * (float)g0[0];
        ay += e0 * (float)g0[1];
        az += e0 * (float)g0[2];
        aw += e0 * (float)g0[3];
    }
    float inv = (end > beg) ? (1.0f / s) : 0.f;
    ushort4 oh, ol;
    float v;
    v = ax * inv; v = (v > 0.f) ? v : (__expf(v) - 1.f); split_bf(v, oh.x, ol.x);
    v = ay * inv; v = (v > 0.f) ? v : (__expf(v) - 1.f); split_bf(v, oh.y, ol.y);
    v = az * inv; v = (v > 0.f) ? v : (__expf(v) - 1.f); split_bf(v, oh.z, ol.z);
    v = aw * inv; v = (v > 0.f) ? v : (__expf(v) - 1.f); split_bf(v, oh.w, ol.w);
    const int rtg = node >> 4;
    const int kb = dbase >> 5;
    const int li = (node & 15) + ((dbase >> 3) & 3) * 16;
    const size_t idx = ((size_t)rtg * 8 + kb) * 512 + li * 8 + (dbase & 7);
    *(ushort4*)&h0H[idx] = oh;
    *(ushort4*)&h0L[idx] = ol;
}

// ---------------- layer 1 edge kernel: packed score, no-max, 4 edges in flight ----

__global__ __launch_bounds__(256) void gat_edge1(const _Float16* __restrict__ feat,
                                                 const float* __restrict__ attn,
                                                 const int* __restrict__ rowptr,
                                                 const int* __restrict__ csr,
                                                 float* __restrict__ out) {
    const int lane = threadIdx.x & 63;
    const int node = blockIdx.x * 4 + (threadIdx.x >> 6);
    if (node >= N_NODES) return;
    const int g = lane >> 4;
    const int d0 = (lane & 15) * 4;
    const float4 a = *(const float4*)&attn[d0];
    H4 A6, A4;
    A6.h4 = (half4v){(_Float16)(0.6f * LOG2E * a.x), (_Float16)(0.6f * LOG2E * a.y),
                     (_Float16)(0.6f * LOG2E * a.z), (_Float16)(0.6f * LOG2E * a.w)};
    A4.h4 = (half4v){(_Float16)(0.4f * LOG2E * a.x), (_Float16)(0.4f * LOG2E * a.y),
                     (_Float16)(0.4f * LOG2E * a.z), (_Float16)(0.4f * LOG2E * a.w)};
    const char* fbase = (const char*)feat + d0 * 2;
    const half4v fd4 = *(const half4v*)(fbase + ((size_t)node << 7));
    const int beg = rowptr[node], end = rowptr[node + 1];
    float s = 0.f, ax = 0.f, ay = 0.f, az = 0.f, aw = 0.f;
    for (int j = beg + g; j < end; j += 4) {
        half4v g0 = *(const half4v*)(fbase + csr[j]);
        float p = score4(g0, fd4, A6, A4);
        p += __shfl_xor(p, 1);
        p += __shfl_xor(p, 2);
        p += __shfl_xor(p, 4);
        p += __shfl_xor(p, 8);
        float e = __builtin_amdgcn_exp2f(p);
        s  += e;
        ax += e * (float)g0[0];
        ay += e * (float)g0[1];
        az += e * (float)g0[2];
        aw += e * (float)g0[3];
    }
    // merge 4 group partials (plain sums — no max tracking)
#pragma unroll
    for (int off = 16; off <= 32; off <<= 1) {
        s  += __shfl_xor(s, off);
        ax += __shfl_xor(ax, off);
        ay += __shfl_xor(ay, off);
        az += __shfl_xor(az, off);
        aw += __shfl_xor(aw, off);
    }
    if (g == 0) {
        float inv = (end > beg) ? (1.0f / s) : 0.f;
        float4 o = make_float4(ax * inv, ay * inv, az * inv, aw * inv);
        *(float4*)&out[(size_t)node * 64 + d0] = o;
    }
}

// ---------------- launch ----------------

extern "C" void kernel_launch(void* const* d_in, const int* in_sizes, int n_in,
                              void* d_out, int out_size, void* d_ws, size_t ws_size,
                              hipStream_t stream) {
    const float* x     = (const float*)d_in[0];
    const float* W0    = (const float*)d_in[1];
    const float* attn0 = (const float*)d_in[2];
    const float* W1    = (const float*)d_in[3];
    const float* attn1 = (const float*)d_in[4];
    const int*   src0  = (const int*)d_in[5];
    const int*   dst0  = (const int*)d_in[6];
    const int*   src1  = (const int*)d_in[7];
    const int*   dst1  = (const int*)d_in[8];
    float* out = (float*)d_out;

    unsigned short* AHimg = (unsigned short*)d_ws;               // ROWS_PAD*256 (alias h0H)
    unsigned short* ALimg = AHimg + (size_t)ROWS_PAD * 256;      // ROWS_PAD*256 (alias h0L)
    _Float16* feat0h = (_Float16*)(ALimg + (size_t)ROWS_PAD * 256); // N*256 fp16 (alias feat1h)
    unsigned short* W0img = (unsigned short*)(feat0h + (size_t)N_NODES * 256);
    unsigned short* W1img = W0img + 256 * 256;
    unsigned short* h0H = AHimg;
    unsigned short* h0L = ALimg;
    _Float16* feat1h = feat0h;

    int* deg_s    = (int*)(W1img + 64 * 256);
    int* rowptr   = deg_s + 2 * SLN;
    int* rowptr_s = rowptr + 2 * (N_NODES + 1);
    int* cursor_s = rowptr_s + 2 * SLN;
    int* bsum1    = cursor_s + 2 * SLN;
    int* boff1    = bsum1 + 512;
    int* bsum2    = boff1 + 512;
    int* boff2    = bsum2 + 2 * NB2;
    int* tmp      = boff2 + 2 * NB2;
    int* csr      = tmp + 2 * E_EDGES;

    const int eb  = E_EDGES / 256;                 // 3125
    const int nb2 = (SLN + 255) / 256;             // 1563
    const int gb  = ROWS_PAD / 64;                 // 782

    // ---- image builds ----
    k_aimg<<<(N_NODES * 32 + 255) / 256, 256, 0, stream>>>(x, AHimg, ALimg);
    k_wimg<<<(256 * 32 + 255) / 256, 256, 0, stream>>>(W0, W0img, 256);
    k_wimg<<<(64 * 32 + 255) / 256, 256, 0, stream>>>(W1, W1img, 64);

    // ---- CSR build (both layers) ----
    hipMemsetAsync(deg_s, 0, 2 * SLN * sizeof(int), stream);
    k_hist  <<<dim3(eb, 2),  256, 0, stream>>>(dst0, dst1, deg_s);
    k_scan1A<<<dim3(NB1, 2), 256, 0, stream>>>(deg_s, rowptr, bsum1);
    k_scanB <<<2,            256, 0, stream>>>(bsum1, boff1, NB1);
    k_scan1C<<<dim3(NB1, 2), 256, 0, stream>>>(boff1, rowptr);
    k_scan2A<<<dim3(nb2, 2), 256, 0, stream>>>(deg_s, rowptr_s, bsum2);
    k_scan2B<<<2,            256, 0, stream>>>(bsum2, boff2);
    k_scan2C<<<dim3(nb2, 2), 256, 0, stream>>>(deg_s, boff2, rowptr_s, cursor_s);
    k_scatter<<<dim3(eb, 2), 256, 0, stream>>>(src0, dst0, src1, dst1, cursor_s, tmp);
    k_regroup<<<dim3((N_NODES + 3) / 4, 2), 256, 0, stream>>>(deg_s, rowptr_s, rowptr, tmp, csr);

    // ---- layer 0 ----
    mfma_gemm3<256><<<gb, 256, 0, stream>>>(AHimg, ALimg, W0img, feat0h, N_NODES);
    gat_edge0<<<(N_NODES + 3) / 4, 256, 0, stream>>>(feat0h, attn0, rowptr, csr, h0H, h0L);

    // ---- layer 1 ----
    mfma_gemm3<64><<<gb, 256, 0, stream>>>(h0H, h0L, W1img, feat1h, N_NODES);
    gat_edge1<<<(N_NODES + 3) / 4, 256, 0, stream>>>(feat1h, attn1,
                                                     rowptr + (N_NODES + 1), csr + E_EDGES, out);
}

// Round 9
// 323.202 us; speedup vs baseline: 1.2607x; 1.0649x over previous
//
#include <hip/hip_runtime.h>

#define N_NODES 50000
#define E_EDGES 800000
#define NEG_SLOPE 0.2f
#define NSL 8
#define SLN (NSL * N_NODES)          // 400000
#define NB1 196                      // ceil(N/256)
#define NB2 1563                     // ceil(8N/256)
#define ROWS_PAD 50048               // N padded to 64

typedef __attribute__((ext_vector_type(8))) short bf16x8;
typedef __attribute__((ext_vector_type(8))) unsigned short u16x8;
typedef __attribute__((ext_vector_type(4))) float f32x4;
typedef __attribute__((ext_vector_type(4))) _Float16 half4v;
typedef __attribute__((ext_vector_type(2))) _Float16 half2v;

union H4 { half4v h4; half2v h2[2]; unsigned u[2]; };

// truncate-split: f ~= hi + lo with |err| <= 2^-16 |f|
__device__ __forceinline__ void split_bf(float f, unsigned short& h, unsigned short& l) {
    unsigned u = __float_as_uint(f);
    h = (unsigned short)(u >> 16);
    float r = f - __uint_as_float((unsigned)h << 16);
    l = (unsigned short)(__float_as_uint(r) >> 16);
}

__device__ __forceinline__ unsigned short rne_bf(float f) {
    unsigned u = __float_as_uint(f);
    unsigned r = u + 0x7FFF + ((u >> 16) & 1);
    return (unsigned short)(r >> 16);
}

// async global->LDS DMA, 16B/lane; LDS dest = wave-uniform base + lane*16
__device__ __forceinline__ void gload_lds16(const void* g, void* l) {
    __builtin_amdgcn_global_load_lds((__attribute__((address_space(1))) void*)g,
                                     (__attribute__((address_space(3))) void*)l, 16, 0, 0);
}

#define LOG2E 1.4426950408889634f

// packed score: p_log2 = sum_d (0.6*log2e*a_d)*z_d + (0.4*log2e*a_d)*|z_d|
__device__ __forceinline__ float score4(half4v g, half4v fd, const H4& A6, const H4& A4) {
    H4 Z; Z.h4 = g + fd;
    H4 B; B.u[0] = Z.u[0] & 0x7FFF7FFFu; B.u[1] = Z.u[1] & 0x7FFF7FFFu;
    float p = __builtin_amdgcn_fdot2(Z.h2[0], A6.h2[0], 0.0f, false);
    p = __builtin_amdgcn_fdot2(Z.h2[1], A6.h2[1], p, false);
    p = __builtin_amdgcn_fdot2(B.h2[0], A4.h2[0], p, false);
    p = __builtin_amdgcn_fdot2(B.h2[1], A4.h2[1], p, false);
    return p;
}

// ---------------- W image builder (both layers, one dispatch) ----------------
// Fragment image: elem (col,k) -> img[(k/32)*CT*512 + (col/16)*512 + ((col&15)+((k>>3)&3)*16)*8 + (k&7)]

__device__ __forceinline__ void wimg_one(const float* W, unsigned short* img, int Nc, int i) {
    int col = i >> 5, chunk = i & 31;
    int CT = Nc >> 4;
    int kb = chunk >> 2, ct = col >> 4;
    int li = (col & 15) + (chunk & 3) * 16;
    size_t base = ((size_t)kb * CT + ct) * 512 + li * 8;
    unsigned short v[8];
#pragma unroll
    for (int e = 0; e < 8; ++e) v[e] = rne_bf(W[(size_t)(chunk * 8 + e) * Nc + col]);
    *(ushort4*)&img[base]     = make_ushort4(v[0], v[1], v[2], v[3]);
    *(ushort4*)&img[base + 4] = make_ushort4(v[4], v[5], v[6], v[7]);
}

__global__ void k_wimg2(const float* __restrict__ W0, const float* __restrict__ W1,
                        unsigned short* __restrict__ img0, unsigned short* __restrict__ img1) {
    int i = blockIdx.x * blockDim.x + threadIdx.x;
    if (i < 256 * 32) wimg_one(W0, img0, 256, i);
    else if (i < 256 * 32 + 64 * 32) wimg_one(W1, img1, 64, i - 256 * 32);
}

// ---------------- CSR build: slice-local scatter + regroup ----------------

__global__ void k_hist(const int* __restrict__ dst0, const int* __restrict__ dst1,
                       int* __restrict__ deg_s) {
    const int layer = blockIdx.y;
    const int slice = blockIdx.x & (NSL - 1);
    int i = blockIdx.x * blockDim.x + threadIdx.x;
    if (i >= E_EDGES) return;
    int d = (layer == 0) ? dst0[i] : dst1[i];
    atomicAdd(&deg_s[layer * SLN + slice * N_NODES + d], 1);
}

// blocks [0,NB1): node-major degree scan; [NB1,NB1+NB2): flat slice-major scan
__global__ void k_scanA_all(const int* __restrict__ deg_s, int* __restrict__ rowptr,
                            int* __restrict__ bsum1, int* __restrict__ rowptr_s,
                            int* __restrict__ bsum2) {
    const int layer = blockIdx.y;
    __shared__ int lds[256];
    int t = threadIdx.x;
    if (blockIdx.x < NB1) {
        int i = blockIdx.x * 256 + t;
        int v = 0;
        if (i < N_NODES) {
            const int* d = deg_s + layer * SLN + i;
#pragma unroll
            for (int s = 0; s < NSL; ++s) v += d[s * N_NODES];
        }
        lds[t] = v;
        __syncthreads();
        for (int off = 1; off < 256; off <<= 1) {
            int u = (t >= off) ? lds[t - off] : 0;
            __syncthreads();
            lds[t] += u;
            __syncthreads();
        }
        if (i < N_NODES) rowptr[layer * (N_NODES + 1) + i + 1] = lds[t];
        if (t == 255) bsum1[layer * 256 + blockIdx.x] = lds[255];
    } else {
        int bx = blockIdx.x - NB1;
        int i = bx * 256 + t;
        int v = (i < SLN) ? deg_s[layer * SLN + i] : 0;
        lds[t] = v;
        __syncthreads();
        for (int off = 1; off < 256; off <<= 1) {
            int u = (t >= off) ? lds[t - off] : 0;
            __syncthreads();
            lds[t] += u;
            __syncthreads();
        }
        if (i < SLN) rowptr_s[layer * SLN + i] = lds[t];
        if (t == 255) bsum2[layer * NB2 + bx] = lds[255];
    }
}

// blocks 0-1: block-sum scan for scan1 (nb=NB1); blocks 2-3: chunked scan for scan2 (NB2)
__global__ void k_scanB_all(const int* __restrict__ bsum1, int* __restrict__ boff1,
                            const int* __restrict__ bsum2, int* __restrict__ boff2) {
    __shared__ int lds[256];
    __shared__ int carry;
    int t = threadIdx.x;
    if (blockIdx.x < 2) {
        const int layer = blockIdx.x;
        int v = (t < NB1) ? bsum1[layer * 256 + t] : 0;
        lds[t] = v;
        __syncthreads();
        for (int off = 1; off < 256; off <<= 1) {
            int u = (t >= off) ? lds[t - off] : 0;
            __syncthreads();
            lds[t] += u;
            __syncthreads();
        }
        if (t < NB1) boff1[layer * 256 + t] = lds[t] - v;
    } else {
        const int layer = blockIdx.x - 2;
        if (t == 0) carry = 0;
        __syncthreads();
        for (int c = 0; c < NB2; c += 256) {
            int v = (c + t < NB2) ? bsum2[layer * NB2 + c + t] : 0;
            lds[t] = v;
            __syncthreads();
            for (int off = 1; off < 256; off <<= 1) {
                int u = (t >= off) ? lds[t - off] : 0;
                __syncthreads();
                lds[t] += u;
                __syncthreads();
            }
            if (c + t < NB2) boff2[layer * NB2 + c + t] = carry + lds[t] - v;
            __syncthreads();
            if (t == 255) carry += lds[255];
            __syncthreads();
        }
    }
}

// finalize both scans; grid (NB2, 2)
__global__ void k_scanC_all(const int* __restrict__ deg_s, const int* __restrict__ boff1,
                            const int* __restrict__ boff2, int* __restrict__ rowptr,
                            int* __restrict__ rowptr_s, int* __restrict__ cursor_s) {
    const int layer = blockIdx.y;
    int i = blockIdx.x * 256 + threadIdx.x;
    if (i < SLN) {
        const int base = layer * SLN;
        int b = rowptr_s[base + i] + boff2[layer * NB2 + (i >> 8)] - deg_s[base + i];
        rowptr_s[base + i] = b;
        cursor_s[base + i] = b;
    }
    if (i < N_NODES) {
        int* rp = rowptr + layer * (N_NODES + 1);
        rp[i + 1] += boff1[layer * 256 + (i >> 8)];
        if (i == 0) rp[0] = 0;
    }
}

__global__ void k_scatter(const int* __restrict__ src0, const int* __restrict__ dst0,
                          const int* __restrict__ src1, const int* __restrict__ dst1,
                          int* __restrict__ cursor_s, int* __restrict__ tmp) {
    const int layer = blockIdx.y;
    const int slice = blockIdx.x & (NSL - 1);
    int i = blockIdx.x * blockDim.x + threadIdx.x;
    if (i >= E_EDGES) return;
    int s, d;
    if (layer == 0) { s = src0[i]; d = dst0[i]; }
    else            { s = src1[i]; d = dst1[i]; }
    int pos = atomicAdd(&cursor_s[layer * SLN + slice * N_NODES + d], 1);
    tmp[layer * E_EDGES + pos] = s;
}

// regroup writes csr as BYTE offsets of feature rows: <<9 (512B) layer0, <<7 (128B) layer1
__global__ __launch_bounds__(256) void k_regroup(const int* __restrict__ deg_s,
                                                 const int* __restrict__ rowptr_s,
                                                 const int* __restrict__ rowptr,
                                                 const int* __restrict__ tmp,
                                                 int* __restrict__ csr) {
    const int layer = blockIdx.y;
    const int lane = threadIdx.x & 63;
    const int node = blockIdx.x * 4 + (threadIdx.x >> 6);
    if (node >= N_NODES) return;
    const int base = layer * SLN;
    const int sh = (layer == 0) ? 9 : 7;
    int dg = 0, tb = 0;
    if (lane < NSL) {
        dg = deg_s[base + lane * N_NODES + node];
        tb = rowptr_s[base + lane * N_NODES + node];
    }
    int excl = 0, total = 0;
#pragma unroll
    for (int ss = 0; ss < NSL; ++ss) {
        int v = __shfl(dg, ss);
        if (ss < (lane & 7)) excl += v;
        total += v;
    }
    const int base_out = rowptr[layer * (N_NODES + 1) + node];
    const int* tsrc = tmp + (size_t)layer * E_EDGES;
    int* cdst = csr + (size_t)layer * E_EDGES;
    for (int r0 = 0; r0 < total; r0 += 64) {
        int r = r0 + lane;
        bool active = (r < total);
        int rr = active ? r : 0;
        int s = 0;
#pragma unroll
        for (int ss = 1; ss < NSL; ++ss) {
            int e = __shfl(excl, ss);
            if (rr >= e) s = ss;
        }
        int eS  = __shfl(excl, s);
        int tbS = __shfl(tb, s);
        if (active) cdst[base_out + r] = tsrc[tbS + (r - eS)] << sh;
    }
}

// ---------------- layer-0 GEMM: fused split, reg-staged A, image B ----------------
// C[M,256](fp16) = x[M,256] * W0; A split in-register (thread's 32B f32 load IS its
// fragment), ds_write_b128 to lane-consecutive slots; B via linear global_load_lds.

__global__ __launch_bounds__(256, 4) void mfma_gemm4(const float* __restrict__ X,
                                                     const unsigned short* __restrict__ Bimg,
                                                     _Float16* __restrict__ C, int M) {
    constexpr int CT = 16;   // BN = 256
    __shared__ __align__(16) unsigned short AsH[4 * 512];
    __shared__ __align__(16) unsigned short AsL[4 * 512];
    __shared__ __align__(16) unsigned short Bs[CT * 512];

    const int t = threadIdx.x;
    const int w = t >> 6;
    const int lane = t & 63;
    const int r16 = lane & 15;
    const int kg = lane >> 4;
    const int bm = blockIdx.x * 64;
    const int arow = bm + w * 16 + r16;
    const bool rv = (arow < M);
    const float* xsrc = X + (size_t)arow * 256 + kg * 8;

    f32x4 acc[CT];
#pragma unroll
    for (int j = 0; j < CT; ++j) acc[j] = (f32x4){0.f, 0.f, 0.f, 0.f};

    for (int kb = 0; kb < 8; ++kb) {
        float4 v0 = make_float4(0.f, 0.f, 0.f, 0.f);
        float4 v1 = make_float4(0.f, 0.f, 0.f, 0.f);
        if (rv) {
            v0 = *(const float4*)(xsrc + kb * 32);
            v1 = *(const float4*)(xsrc + kb * 32 + 4);
        }
        u16x8 h, l;
        {
            unsigned short hh, ll;
            split_bf(v0.x, hh, ll); h[0] = hh; l[0] = ll;
            split_bf(v0.y, hh, ll); h[1] = hh; l[1] = ll;
            split_bf(v0.z, hh, ll); h[2] = hh; l[2] = ll;
            split_bf(v0.w, hh, ll); h[3] = hh; l[3] = ll;
            split_bf(v1.x, hh, ll); h[4] = hh; l[4] = ll;
            split_bf(v1.y, hh, ll); h[5] = hh; l[5] = ll;
            split_bf(v1.z, hh, ll); h[6] = hh; l[6] = ll;
            split_bf(v1.w, hh, ll); h[7] = hh; l[7] = ll;
        }
        *(u16x8*)&AsH[t * 8] = h;
        *(u16x8*)&AsL[t * 8] = l;
#pragma unroll
        for (int p = 0; p < CT / 4; ++p)
            gload_lds16(Bimg + kb * CT * 512 + p * 2048 + t * 8, &Bs[p * 2048 + w * 512]);
        __syncthreads();

        const bf16x8 aH = *(const bf16x8*)&AsH[t * 8];
        const bf16x8 aL = *(const bf16x8*)&AsL[t * 8];
#pragma unroll
        for (int ct = 0; ct < CT; ++ct) {
            const bf16x8 b = *(const bf16x8*)&Bs[ct * 512 + lane * 8];
            acc[ct] = __builtin_amdgcn_mfma_f32_16x16x32_bf16(aH, b, acc[ct], 0, 0, 0);
            acc[ct] = __builtin_amdgcn_mfma_f32_16x16x32_bf16(aL, b, acc[ct], 0, 0, 0);
        }
        __syncthreads();
    }

#pragma unroll
    for (int r = 0; r < 4; ++r) {
        int row = bm + w * 16 + kg * 4 + r;
        if (row < M) {
#pragma unroll
            for (int ct = 0; ct < CT; ++ct)
                C[(size_t)row * 256 + ct * 16 + r16] = (_Float16)acc[ct][r];
        }
    }
}

// ---------------- layer-1 GEMM: image A (written by edge0), image B ----------------

template<int BN>
__global__ __launch_bounds__(256, 4) void mfma_gemm3(const unsigned short* __restrict__ AH,
                                                     const unsigned short* __restrict__ AL,
                                                     const unsigned short* __restrict__ Bimg,
                                                     _Float16* __restrict__ C, int M) {
    constexpr int CT = BN / 16;
    __shared__ __align__(16) unsigned short AsH[4 * 512];
    __shared__ __align__(16) unsigned short AsL[4 * 512];
    __shared__ __align__(16) unsigned short Bs[CT * 512];

    const int t = threadIdx.x;
    const int w = t >> 6;
    const int lane = t & 63;
    const int r16 = lane & 15;
    const int kg = lane >> 4;
    const int bm = blockIdx.x * 64;

    f32x4 acc[CT];
#pragma unroll
    for (int j = 0; j < CT; ++j) acc[j] = (f32x4){0.f, 0.f, 0.f, 0.f};

    const size_t abase = ((size_t)(blockIdx.x * 4 + w)) * 8 * 512;  // shorts

    for (int kb = 0; kb < 8; ++kb) {
        gload_lds16(AH + abase + kb * 512 + lane * 8, &AsH[w * 512]);
        gload_lds16(AL + abase + kb * 512 + lane * 8, &AsL[w * 512]);
#pragma unroll
        for (int p = 0; p < CT / 4; ++p)
            gload_lds16(Bimg + kb * CT * 512 + p * 2048 + t * 8, &Bs[p * 2048 + w * 512]);
        __syncthreads();

        const bf16x8 aH = *(const bf16x8*)&AsH[w * 512 + lane * 8];
        const bf16x8 aL = *(const bf16x8*)&AsL[w * 512 + lane * 8];
#pragma unroll
        for (int ct = 0; ct < CT; ++ct) {
            const bf16x8 b = *(const bf16x8*)&Bs[ct * 512 + lane * 8];
            acc[ct] = __builtin_amdgcn_mfma_f32_16x16x32_bf16(aH, b, acc[ct], 0, 0, 0);
            acc[ct] = __builtin_amdgcn_mfma_f32_16x16x32_bf16(aL, b, acc[ct], 0, 0, 0);
        }
        __syncthreads();
    }

#pragma unroll
    for (int r = 0; r < 4; ++r) {
        int row = bm + w * 16 + kg * 4 + r;
        if (row < M) {
#pragma unroll
            for (int ct = 0; ct < CT; ++ct)
                C[(size_t)row * BN + ct * 16 + r16] = (_Float16)acc[ct][r];
        }
    }
}

// ---------------- layer 0 edge kernel: packed fp16 score, no-max softmax ----------------

__global__ __launch_bounds__(256) void gat_edge0(const _Float16* __restrict__ feat,
                                                 const float* __restrict__ attn,
                                                 const int* __restrict__ rowptr,
                                                 const int* __restrict__ csr,
                                                 unsigned short* __restrict__ h0H,
                                                 unsigned short* __restrict__ h0L) {
    const int lane = threadIdx.x & 63;
    const int node = blockIdx.x * 4 + (threadIdx.x >> 6);
    if (node >= N_NODES) return;
    const int dbase = ((lane >> 4) << 6) + (lane & 15) * 4;
    const float4 a = *(const float4*)&attn[dbase];
    H4 A6, A4;
    A6.h4 = (half4v){(_Float16)(0.6f * LOG2E * a.x), (_Float16)(0.6f * LOG2E * a.y),
                     (_Float16)(0.6f * LOG2E * a.z), (_Float16)(0.6f * LOG2E * a.w)};
    A4.h4 = (half4v){(_Float16)(0.4f * LOG2E * a.x), (_Float16)(0.4f * LOG2E * a.y),
                     (_Float16)(0.4f * LOG2E * a.z), (_Float16)(0.4f * LOG2E * a.w)};
    const char* fbase = (const char*)feat + dbase * 2;
    const half4v fd4 = *(const half4v*)(fbase + ((size_t)node << 9));
    const int beg = rowptr[node], end = rowptr[node + 1];
    float s = 0.f, ax = 0.f, ay = 0.f, az = 0.f, aw = 0.f;
    int j = beg;
    for (; j + 3 < end; j += 4) {
        int o0 = csr[j], o1 = csr[j + 1], o2 = csr[j + 2], o3 = csr[j + 3];
        half4v g0 = *(const half4v*)(fbase + o0);
        half4v g1 = *(const half4v*)(fbase + o1);
        half4v g2 = *(const half4v*)(fbase + o2);
        half4v g3 = *(const half4v*)(fbase + o3);
        float p0 = score4(g0, fd4, A6, A4);
        float p1 = score4(g1, fd4, A6, A4);
        float p2 = score4(g2, fd4, A6, A4);
        float p3 = score4(g3, fd4, A6, A4);
        p0 += __shfl_xor(p0, 1); p1 += __shfl_xor(p1, 1); p2 += __shfl_xor(p2, 1); p3 += __shfl_xor(p3, 1);
        p0 += __shfl_xor(p0, 2); p1 += __shfl_xor(p1, 2); p2 += __shfl_xor(p2, 2); p3 += __shfl_xor(p3, 2);
        p0 += __shfl_xor(p0, 4); p1 += __shfl_xor(p1, 4); p2 += __shfl_xor(p2, 4); p3 += __shfl_xor(p3, 4);
        p0 += __shfl_xor(p0, 8); p1 += __shfl_xor(p1, 8); p2 += __shfl_xor(p2, 8); p3 += __shfl_xor(p3, 8);
        float e0 = __builtin_amdgcn_exp2f(p0);
        float e1 = __builtin_amdgcn_exp2f(p1);
        float e2 = __builtin_amdgcn_exp2f(p2);
        float e3 = __builtin_amdgcn_exp2f(p3);
        s  += e0 + e1 + e2 + e3;
        ax += e0 * (float)g0[0] + e1 * (float)g1[0] + e2 * (float)g2[0] + e3 * (float)g3[0];
        ay += e0 * (float)g0[1] + e1 * (float)g1[1] + e2 * (float)g2[1] + e3 * (float)g3[1];
        az += e0 * (float)g0[2] + e1 * (float)g1[2] + e2 * (float)g2[2] + e3 * (float)g3[2];
        aw += e0 * (float)g0[3] + e1 * (float)g1[3] + e2 * (float)g2[3] + e3 * (float)g3[3];
    }
    for (; j < end; ++j) {
        half4v g0 = *(const half4v*)(fbase + csr[j]);
        float p0 = score4(g0, fd4, A6, A4);
        p0 += __shfl_xor(p0, 1);
        p0 += __shfl_xor(p0, 2);
        p0 += __shfl_xor(p0, 4);
        p0 += __shfl_xor(p0, 8);
        float e0 = __builtin_amdgcn_exp2f(p0);
        s  += e0;
        ax += e0 * (float)g0[0];
        ay += e0 * (float)g0[1];
        az += e0 * (float)g0[2];
        aw += e0 * (float)g0[3];
    }
    float inv = (end > beg) ? (1.0f / s) : 0.f;
    ushort4 oh, ol;
    float v;
    v = ax * inv; v = (v > 0.f) ? v : (__expf(v) - 1.f); split_bf(v, oh.x, ol.x);
    v = ay * inv; v = (v > 0.f) ? v : (__expf(v) - 1.f); split_bf(v, oh.y, ol.y);
    v = az * inv; v = (v > 0.f) ? v : (__expf(v) - 1.f); split_bf(v, oh.z, ol.z);
    v = aw * inv; v = (v > 0.f) ? v : (__expf(v) - 1.f); split_bf(v, oh.w, ol.w);
    const int rtg = node >> 4;
    const int kb = dbase >> 5;
    const int li = (node & 15) + ((dbase >> 3) & 3) * 16;
    const size_t idx = ((size_t)rtg * 8 + kb) * 512 + li * 8 + (dbase & 7);
    *(ushort4*)&h0H[idx] = oh;
    *(ushort4*)&h0L[idx] = ol;
}

// ---------------- layer 1 edge kernel: packed score, no-max, 4 edges in flight ----

__global__ __launch_bounds__(256) void gat_edge1(const _Float16* __restrict__ feat,
                                                 const float* __restrict__ attn,
                                                 const int* __restrict__ rowptr,
                                                 const int* __restrict__ csr,
                                                 float* __restrict__ out) {
    const int lane = threadIdx.x & 63;
    const int node = blockIdx.x * 4 + (threadIdx.x >> 6);
    if (node >= N_NODES) return;
    const int g = lane >> 4;
    const int d0 = (lane & 15) * 4;
    const float4 a = *(const float4*)&attn[d0];
    H4 A6, A4;
    A6.h4 = (half4v){(_Float16)(0.6f * LOG2E * a.x), (_Float16)(0.6f * LOG2E * a.y),
                     (_Float16)(0.6f * LOG2E * a.z), (_Float16)(0.6f * LOG2E * a.w)};
    A4.h4 = (half4v){(_Float16)(0.4f * LOG2E * a.x), (_Float16)(0.4f * LOG2E * a.y),
                     (_Float16)(0.4f * LOG2E * a.z), (_Float16)(0.4f * LOG2E * a.w)};
    const char* fbase = (const char*)feat + d0 * 2;
    const half4v fd4 = *(const half4v*)(fbase + ((size_t)node << 7));
    const int beg = rowptr[node], end = rowptr[node + 1];
    float s = 0.f, ax = 0.f, ay = 0.f, az = 0.f, aw = 0.f;
    for (int j = beg + g; j < end; j += 4) {
        half4v g0 = *(const half4v*)(fbase + csr[j]);
        float p = score4(g0, fd4, A6, A4);
        p += __shfl_xor(p, 1);
        p += __shfl_xor(p, 2);
        p += __shfl_xor(p, 4);
        p += __shfl_xor(p, 8);
        float e = __builtin_amdgcn_exp2f(p);
        s  += e;
        ax += e * (float)g0[0];
        ay += e * (float)g0[1];
        az += e * (float)g0[2];
        aw += e * (float)g0[3];
    }
#pragma unroll
    for (int off = 16; off <= 32; off <<= 1) {
        s  += __shfl_xor(s, off);
        ax += __shfl_xor(ax, off);
        ay += __shfl_xor(ay, off);
        az += __shfl_xor(az, off);
        aw += __shfl_xor(aw, off);
    }
    if (g == 0) {
        float inv = (end > beg) ? (1.0f / s) : 0.f;
        float4 o = make_float4(ax * inv, ay * inv, az * inv, aw * inv);
        *(float4*)&out[(size_t)node * 64 + d0] = o;
    }
}

// ---------------- launch ----------------

extern "C" void kernel_launch(void* const* d_in, const int* in_sizes, int n_in,
                              void* d_out, int out_size, void* d_ws, size_t ws_size,
                              hipStream_t stream) {
    const float* x     = (const float*)d_in[0];
    const float* W0    = (const float*)d_in[1];
    const float* attn0 = (const float*)d_in[2];
    const float* W1    = (const float*)d_in[3];
    const float* attn1 = (const float*)d_in[4];
    const int*   src0  = (const int*)d_in[5];
    const int*   dst0  = (const int*)d_in[6];
    const int*   src1  = (const int*)d_in[7];
    const int*   dst1  = (const int*)d_in[8];
    float* out = (float*)d_out;

    unsigned short* h0H = (unsigned short*)d_ws;                 // ROWS_PAD*256 (image)
    unsigned short* h0L = h0H + (size_t)ROWS_PAD * 256;          // ROWS_PAD*256 (image)
    _Float16* feat0h = (_Float16*)(h0L + (size_t)ROWS_PAD * 256); // N*256 fp16 (alias feat1h)
    unsigned short* W0img = (unsigned short*)(feat0h + (size_t)N_NODES * 256);
    unsigned short* W1img = W0img + 256 * 256;
    _Float16* feat1h = feat0h;

    int* deg_s    = (int*)(W1img + 64 * 256);
    int* rowptr   = deg_s + 2 * SLN;
    int* rowptr_s = rowptr + 2 * (N_NODES + 1);
    int* cursor_s = rowptr_s + 2 * SLN;
    int* bsum1    = cursor_s + 2 * SLN;
    int* boff1    = bsum1 + 512;
    int* bsum2    = boff1 + 512;
    int* boff2    = bsum2 + 2 * NB2;
    int* tmp      = boff2 + 2 * NB2;
    int* csr      = tmp + 2 * E_EDGES;

    const int eb = E_EDGES / 256;                  // 3125
    const int gb = ROWS_PAD / 64;                  // 782

    // ---- W images (one dispatch) ----
    k_wimg2<<<(256 * 32 + 64 * 32 + 255) / 256, 256, 0, stream>>>(W0, W1, W0img, W1img);

    // ---- CSR build (both layers) ----
    hipMemsetAsync(deg_s, 0, 2 * SLN * sizeof(int), stream);
    k_hist     <<<dim3(eb, 2),        256, 0, stream>>>(dst0, dst1, deg_s);
    k_scanA_all<<<dim3(NB1 + NB2, 2), 256, 0, stream>>>(deg_s, rowptr, bsum1, rowptr_s, bsum2);
    k_scanB_all<<<4,                  256, 0, stream>>>(bsum1, boff1, bsum2, boff2);
    k_scanC_all<<<dim3(NB2, 2),       256, 0, stream>>>(deg_s, boff1, boff2, rowptr, rowptr_s, cursor_s);
    k_scatter  <<<dim3(eb, 2),        256, 0, stream>>>(src0, dst0, src1, dst1, cursor_s, tmp);
    k_regroup  <<<dim3((N_NODES + 3) / 4, 2), 256, 0, stream>>>(deg_s, rowptr_s, rowptr, tmp, csr);

    // ---- layer 0 ----
    mfma_gemm4<<<gb, 256, 0, stream>>>(x, W0img, feat0h, N_NODES);
    gat_edge0<<<(N_NODES + 3) / 4, 256, 0, stream>>>(feat0h, attn0, rowptr, csr, h0H, h0L);

    // ---- layer 1 ----
    mfma_gemm3<64><<<gb, 256, 0, stream>>>(h0H, h0L, W1img, feat1h, N_NODES);
    gat_edge1<<<(N_NODES + 3) / 4, 256, 0, stream>>>(feat1h, attn1,
                                                     rowptr + (N_NODES + 1), csr + E_EDGES, out);
}

// Round 10
// 302.260 us; speedup vs baseline: 1.3480x; 1.0693x over previous
//
#include <hip/hip_runtime.h>

#define N_NODES 50000
#define E_EDGES 800000
#define NEG_SLOPE 0.2f
#define NSL 8
#define SLN (NSL * N_NODES)          // 400000
#define NB1 196                      // ceil(N/256)
#define NB2 1563                     // ceil(8N/256)
#define ROWS_PAD 50048               // N padded to 64

typedef __attribute__((ext_vector_type(8))) _Float16 f16x8;
typedef __attribute__((ext_vector_type(4))) float f32x4;
typedef __attribute__((ext_vector_type(4))) _Float16 half4v;
typedef __attribute__((ext_vector_type(2))) _Float16 half2v;

union H4 { half4v h4; half2v h2[2]; unsigned u[2]; };

// truncate-split (edge0 epilogue no longer needs it; kept for nothing else) — removed.

// async global->LDS DMA, 16B/lane; LDS dest = wave-uniform base + lane*16
__device__ __forceinline__ void gload_lds16(const void* g, void* l) {
    __builtin_amdgcn_global_load_lds((__attribute__((address_space(1))) void*)g,
                                     (__attribute__((address_space(3))) void*)l, 16, 0, 0);
}

#define LOG2E 1.4426950408889634f

// packed score: p_log2 = sum_d (0.6*log2e*a_d)*z_d + (0.4*log2e*a_d)*|z_d|
__device__ __forceinline__ float score4(half4v g, half4v fd, const H4& A6, const H4& A4) {
    H4 Z; Z.h4 = g + fd;
    H4 B; B.u[0] = Z.u[0] & 0x7FFF7FFFu; B.u[1] = Z.u[1] & 0x7FFF7FFFu;
    float p = __builtin_amdgcn_fdot2(Z.h2[0], A6.h2[0], 0.0f, false);
    p = __builtin_amdgcn_fdot2(Z.h2[1], A6.h2[1], p, false);
    p = __builtin_amdgcn_fdot2(B.h2[0], A4.h2[0], p, false);
    p = __builtin_amdgcn_fdot2(B.h2[1], A4.h2[1], p, false);
    return p;
}

// ---------------- W image builder (both layers, one dispatch, fp16) ----------------
// Fragment image: elem (col,k) -> img[(k/32)*CT*512 + (col/16)*512 + ((col&15)+((k>>3)&3)*16)*8 + (k&7)]

__device__ __forceinline__ void wimg_one(const float* W, _Float16* img, int Nc, int i) {
    int col = i >> 5, chunk = i & 31;
    int CT = Nc >> 4;
    int kb = chunk >> 2, ct = col >> 4;
    int li = (col & 15) + (chunk & 3) * 16;
    size_t base = ((size_t)kb * CT + ct) * 512 + li * 8;
    half4v v0, v1;
#pragma unroll
    for (int e = 0; e < 4; ++e) v0[e] = (_Float16)W[(size_t)(chunk * 8 + e) * Nc + col];
#pragma unroll
    for (int e = 0; e < 4; ++e) v1[e] = (_Float16)W[(size_t)(chunk * 8 + 4 + e) * Nc + col];
    *(half4v*)&img[base]     = v0;
    *(half4v*)&img[base + 4] = v1;
}

__global__ void k_wimg2(const float* __restrict__ W0, const float* __restrict__ W1,
                        _Float16* __restrict__ img0, _Float16* __restrict__ img1) {
    int i = blockIdx.x * blockDim.x + threadIdx.x;
    if (i < 256 * 32) wimg_one(W0, img0, 256, i);
    else if (i < 256 * 32 + 64 * 32) wimg_one(W1, img1, 64, i - 256 * 32);
}

// ---------------- CSR build: slice-local scatter + regroup ----------------

__global__ void k_hist(const int* __restrict__ dst0, const int* __restrict__ dst1,
                       int* __restrict__ deg_s) {
    const int layer = blockIdx.y;
    const int slice = blockIdx.x & (NSL - 1);
    int i = blockIdx.x * blockDim.x + threadIdx.x;
    if (i >= E_EDGES) return;
    int d = (layer == 0) ? dst0[i] : dst1[i];
    atomicAdd(&deg_s[layer * SLN + slice * N_NODES + d], 1);
}

__global__ void k_scanA_all(const int* __restrict__ deg_s, int* __restrict__ rowptr,
                            int* __restrict__ bsum1, int* __restrict__ rowptr_s,
                            int* __restrict__ bsum2) {
    const int layer = blockIdx.y;
    __shared__ int lds[256];
    int t = threadIdx.x;
    if (blockIdx.x < NB1) {
        int i = blockIdx.x * 256 + t;
        int v = 0;
        if (i < N_NODES) {
            const int* d = deg_s + layer * SLN + i;
#pragma unroll
            for (int s = 0; s < NSL; ++s) v += d[s * N_NODES];
        }
        lds[t] = v;
        __syncthreads();
        for (int off = 1; off < 256; off <<= 1) {
            int u = (t >= off) ? lds[t - off] : 0;
            __syncthreads();
            lds[t] += u;
            __syncthreads();
        }
        if (i < N_NODES) rowptr[layer * (N_NODES + 1) + i + 1] = lds[t];
        if (t == 255) bsum1[layer * 256 + blockIdx.x] = lds[255];
    } else {
        int bx = blockIdx.x - NB1;
        int i = bx * 256 + t;
        int v = (i < SLN) ? deg_s[layer * SLN + i] : 0;
        lds[t] = v;
        __syncthreads();
        for (int off = 1; off < 256; off <<= 1) {
            int u = (t >= off) ? lds[t - off] : 0;
            __syncthreads();
            lds[t] += u;
            __syncthreads();
        }
        if (i < SLN) rowptr_s[layer * SLN + i] = lds[t];
        if (t == 255) bsum2[layer * NB2 + bx] = lds[255];
    }
}

__global__ void k_scanB_all(const int* __restrict__ bsum1, int* __restrict__ boff1,
                            const int* __restrict__ bsum2, int* __restrict__ boff2) {
    __shared__ int lds[256];
    __shared__ int carry;
    int t = threadIdx.x;
    if (blockIdx.x < 2) {
        const int layer = blockIdx.x;
        int v = (t < NB1) ? bsum1[layer * 256 + t] : 0;
        lds[t] = v;
        __syncthreads();
        for (int off = 1; off < 256; off <<= 1) {
            int u = (t >= off) ? lds[t - off] : 0;
            __syncthreads();
            lds[t] += u;
            __syncthreads();
        }
        if (t < NB1) boff1[layer * 256 + t] = lds[t] - v;
    } else {
        const int layer = blockIdx.x - 2;
        if (t == 0) carry = 0;
        __syncthreads();
        for (int c = 0; c < NB2; c += 256) {
            int v = (c + t < NB2) ? bsum2[layer * NB2 + c + t] : 0;
            lds[t] = v;
            __syncthreads();
            for (int off = 1; off < 256; off <<= 1) {
                int u = (t >= off) ? lds[t - off] : 0;
                __syncthreads();
                lds[t] += u;
                __syncthreads();
            }
            if (c + t < NB2) boff2[layer * NB2 + c + t] = carry + lds[t] - v;
            __syncthreads();
            if (t == 255) carry += lds[255];
            __syncthreads();
        }
    }
}

__global__ void k_scanC_all(const int* __restrict__ deg_s, const int* __restrict__ boff1,
                            const int* __restrict__ boff2, int* __restrict__ rowptr,
                            int* __restrict__ rowptr_s, int* __restrict__ cursor_s) {
    const int layer = blockIdx.y;
    int i = blockIdx.x * 256 + threadIdx.x;
    if (i < SLN) {
        const int base = layer * SLN;
        int b = rowptr_s[base + i] + boff2[layer * NB2 + (i >> 8)] - deg_s[base + i];
        rowptr_s[base + i] = b;
        cursor_s[base + i] = b;
    }
    if (i < N_NODES) {
        int* rp = rowptr + layer * (N_NODES + 1);
        rp[i + 1] += boff1[layer * 256 + (i >> 8)];
        if (i == 0) rp[0] = 0;
    }
}

__global__ void k_scatter(const int* __restrict__ src0, const int* __restrict__ dst0,
                          const int* __restrict__ src1, const int* __restrict__ dst1,
                          int* __restrict__ cursor_s, int* __restrict__ tmp) {
    const int layer = blockIdx.y;
    const int slice = blockIdx.x & (NSL - 1);
    int i = blockIdx.x * blockDim.x + threadIdx.x;
    if (i >= E_EDGES) return;
    int s, d;
    if (layer == 0) { s = src0[i]; d = dst0[i]; }
    else            { s = src1[i]; d = dst1[i]; }
    int pos = atomicAdd(&cursor_s[layer * SLN + slice * N_NODES + d], 1);
    tmp[layer * E_EDGES + pos] = s;
}

// regroup writes csr as BYTE offsets of feature rows: <<9 (512B) layer0, <<7 (128B) layer1
__global__ __launch_bounds__(256) void k_regroup(const int* __restrict__ deg_s,
                                                 const int* __restrict__ rowptr_s,
                                                 const int* __restrict__ rowptr,
                                                 const int* __restrict__ tmp,
                                                 int* __restrict__ csr) {
    const int layer = blockIdx.y;
    const int lane = threadIdx.x & 63;
    const int node = blockIdx.x * 4 + (threadIdx.x >> 6);
    if (node >= N_NODES) return;
    const int base = layer * SLN;
    const int sh = (layer == 0) ? 9 : 7;
    int dg = 0, tb = 0;
    if (lane < NSL) {
        dg = deg_s[base + lane * N_NODES + node];
        tb = rowptr_s[base + lane * N_NODES + node];
    }
    int excl = 0, total = 0;
#pragma unroll
    for (int ss = 0; ss < NSL; ++ss) {
        int v = __shfl(dg, ss);
        if (ss < (lane & 7)) excl += v;
        total += v;
    }
    const int base_out = rowptr[layer * (N_NODES + 1) + node];
    const int* tsrc = tmp + (size_t)layer * E_EDGES;
    int* cdst = csr + (size_t)layer * E_EDGES;
    for (int r0 = 0; r0 < total; r0 += 64) {
        int r = r0 + lane;
        bool active = (r < total);
        int rr = active ? r : 0;
        int s = 0;
#pragma unroll
        for (int ss = 1; ss < NSL; ++ss) {
            int e = __shfl(excl, ss);
            if (rr >= e) s = ss;
        }
        int eS  = __shfl(excl, s);
        int tbS = __shfl(tb, s);
        if (active) cdst[base_out + r] = tsrc[tbS + (r - eS)] << sh;
    }
}

// ---------------- layer-0 GEMM: fp16 MFMA, reg-staged A (fused f32->fp16), image B ----

__global__ __launch_bounds__(256, 4) void mfma_gemm4f(const float* __restrict__ X,
                                                      const _Float16* __restrict__ Bimg,
                                                      _Float16* __restrict__ C, int M) {
    constexpr int CT = 16;   // BN = 256
    __shared__ __align__(16) _Float16 AsF[4 * 512];
    __shared__ __align__(16) _Float16 Bs[CT * 512];

    const int t = threadIdx.x;
    const int w = t >> 6;
    const int lane = t & 63;
    const int r16 = lane & 15;
    const int kg = lane >> 4;
    const int bm = blockIdx.x * 64;
    const int arow = bm + w * 16 + r16;
    const bool rv = (arow < M);
    const float* xsrc = X + (size_t)arow * 256 + kg * 8;

    f32x4 acc[CT];
#pragma unroll
    for (int j = 0; j < CT; ++j) acc[j] = (f32x4){0.f, 0.f, 0.f, 0.f};

    for (int kb = 0; kb < 8; ++kb) {
        float4 v0 = make_float4(0.f, 0.f, 0.f, 0.f);
        float4 v1 = make_float4(0.f, 0.f, 0.f, 0.f);
        if (rv) {
            v0 = *(const float4*)(xsrc + kb * 32);
            v1 = *(const float4*)(xsrc + kb * 32 + 4);
        }
        f16x8 af;
        af[0] = (_Float16)v0.x; af[1] = (_Float16)v0.y;
        af[2] = (_Float16)v0.z; af[3] = (_Float16)v0.w;
        af[4] = (_Float16)v1.x; af[5] = (_Float16)v1.y;
        af[6] = (_Float16)v1.z; af[7] = (_Float16)v1.w;
        *(f16x8*)&AsF[t * 8] = af;
#pragma unroll
        for (int p = 0; p < CT / 4; ++p)
            gload_lds16(Bimg + kb * CT * 512 + p * 2048 + t * 8, &Bs[p * 2048 + w * 512]);
        __syncthreads();

        const f16x8 aF = *(const f16x8*)&AsF[t * 8];
#pragma unroll
        for (int ct = 0; ct < CT; ++ct) {
            const f16x8 b = *(const f16x8*)&Bs[ct * 512 + lane * 8];
            acc[ct] = __builtin_amdgcn_mfma_f32_16x16x32_f16(aF, b, acc[ct], 0, 0, 0);
        }
        __syncthreads();
    }

#pragma unroll
    for (int r = 0; r < 4; ++r) {
        int row = bm + w * 16 + kg * 4 + r;
        if (row < M) {
#pragma unroll
            for (int ct = 0; ct < CT; ++ct)
                C[(size_t)row * 256 + ct * 16 + r16] = (_Float16)acc[ct][r];
        }
    }
}

// ---------------- layer-1 GEMM: fp16 image A (written by edge0), fp16 image B ----------

template<int BN>
__global__ __launch_bounds__(256, 4) void mfma_gemm3f(const _Float16* __restrict__ Aimg,
                                                      const _Float16* __restrict__ Bimg,
                                                      _Float16* __restrict__ C, int M) {
    constexpr int CT = BN / 16;
    __shared__ __align__(16) _Float16 AsF[4 * 512];
    __shared__ __align__(16) _Float16 Bs[CT * 512];

    const int t = threadIdx.x;
    const int w = t >> 6;
    const int lane = t & 63;
    const int r16 = lane & 15;
    const int kg = lane >> 4;
    const int bm = blockIdx.x * 64;

    f32x4 acc[CT];
#pragma unroll
    for (int j = 0; j < CT; ++j) acc[j] = (f32x4){0.f, 0.f, 0.f, 0.f};

    const size_t abase = ((size_t)(blockIdx.x * 4 + w)) * 8 * 512;  // elements

    for (int kb = 0; kb < 8; ++kb) {
        gload_lds16(Aimg + abase + kb * 512 + lane * 8, &AsF[w * 512]);
#pragma unroll
        for (int p = 0; p < (CT + 3) / 4; ++p)
            gload_lds16(Bimg + kb * CT * 512 + p * 2048 + t * 8, &Bs[p * 2048 + w * 512]);
        __syncthreads();

        const f16x8 aF = *(const f16x8*)&AsF[w * 512 + lane * 8];
#pragma unroll
        for (int ct = 0; ct < CT; ++ct) {
            const f16x8 b = *(const f16x8*)&Bs[ct * 512 + lane * 8];
            acc[ct] = __builtin_amdgcn_mfma_f32_16x16x32_f16(aF, b, acc[ct], 0, 0, 0);
        }
        __syncthreads();
    }

#pragma unroll
    for (int r = 0; r < 4; ++r) {
        int row = bm + w * 16 + kg * 4 + r;
        if (row < M) {
#pragma unroll
            for (int ct = 0; ct < CT; ++ct)
                C[(size_t)row * BN + ct * 16 + r16] = (_Float16)acc[ct][r];
        }
    }
}

// ---------------- layer 0 edge kernel: packed fp16 score, no-max, 8-edge unroll ----

__global__ __launch_bounds__(256) void gat_edge0(const _Float16* __restrict__ feat,
                                                 const float* __restrict__ attn,
                                                 const int* __restrict__ rowptr,
                                                 const int* __restrict__ csr,
                                                 _Float16* __restrict__ h0img) {
    const int lane = threadIdx.x & 63;
    const int node = blockIdx.x * 4 + (threadIdx.x >> 6);
    if (node >= N_NODES) return;
    const int dbase = ((lane >> 4) << 6) + (lane & 15) * 4;
    const float4 a = *(const float4*)&attn[dbase];
    H4 A6, A4;
    A6.h4 = (half4v){(_Float16)(0.6f * LOG2E * a.x), (_Float16)(0.6f * LOG2E * a.y),
                     (_Float16)(0.6f * LOG2E * a.z), (_Float16)(0.6f * LOG2E * a.w)};
    A4.h4 = (half4v){(_Float16)(0.4f * LOG2E * a.x), (_Float16)(0.4f * LOG2E * a.y),
                     (_Float16)(0.4f * LOG2E * a.z), (_Float16)(0.4f * LOG2E * a.w)};
    const char* fbase = (const char*)feat + dbase * 2;
    const half4v fd4 = *(const half4v*)(fbase + ((size_t)node << 9));
    const int beg = rowptr[node], end = rowptr[node + 1];
    float s = 0.f, ax = 0.f, ay = 0.f, az = 0.f, aw = 0.f;
    int j = beg;
    for (; j + 7 < end; j += 8) {
        half4v g[8];
        float p[8];
#pragma unroll
        for (int i = 0; i < 8; ++i) g[i] = *(const half4v*)(fbase + csr[j + i]);
#pragma unroll
        for (int i = 0; i < 8; ++i) p[i] = score4(g[i], fd4, A6, A4);
#pragma unroll
        for (int r = 1; r <= 8; r <<= 1)
#pragma unroll
            for (int i = 0; i < 8; ++i) p[i] += __shfl_xor(p[i], r);
        float e[8];
#pragma unroll
        for (int i = 0; i < 8; ++i) e[i] = __builtin_amdgcn_exp2f(p[i]);
#pragma unroll
        for (int i = 0; i < 8; ++i) {
            s  += e[i];
            ax += e[i] * (float)g[i][0];
            ay += e[i] * (float)g[i][1];
            az += e[i] * (float)g[i][2];
            aw += e[i] * (float)g[i][3];
        }
    }
    if (j + 3 < end) {
        half4v g[4];
        float p[4];
#pragma unroll
        for (int i = 0; i < 4; ++i) g[i] = *(const half4v*)(fbase + csr[j + i]);
#pragma unroll
        for (int i = 0; i < 4; ++i) p[i] = score4(g[i], fd4, A6, A4);
#pragma unroll
        for (int r = 1; r <= 8; r <<= 1)
#pragma unroll
            for (int i = 0; i < 4; ++i) p[i] += __shfl_xor(p[i], r);
#pragma unroll
        for (int i = 0; i < 4; ++i) {
            float e = __builtin_amdgcn_exp2f(p[i]);
            s  += e;
            ax += e * (float)g[i][0];
            ay += e * (float)g[i][1];
            az += e * (float)g[i][2];
            aw += e * (float)g[i][3];
        }
        j += 4;
    }
    for (; j < end; ++j) {
        half4v g0 = *(const half4v*)(fbase + csr[j]);
        float p0 = score4(g0, fd4, A6, A4);
        p0 += __shfl_xor(p0, 1);
        p0 += __shfl_xor(p0, 2);
        p0 += __shfl_xor(p0, 4);
        p0 += __shfl_xor(p0, 8);
        float e0 = __builtin_amdgcn_exp2f(p0);
        s  += e0;
        ax += e0 * (float)g0[0];
        ay += e0 * (float)g0[1];
        az += e0 * (float)g0[2];
        aw += e0 * (float)g0[3];
    }
    float inv = (end > beg) ? (1.0f / s) : 0.f;
    half4v o;
    float v;
    v = ax * inv; o[0] = (_Float16)((v > 0.f) ? v : (__expf(v) - 1.f));
    v = ay * inv; o[1] = (_Float16)((v > 0.f) ? v : (__expf(v) - 1.f));
    v = az * inv; o[2] = (_Float16)((v > 0.f) ? v : (__expf(v) - 1.f));
    v = aw * inv; o[3] = (_Float16)((v > 0.f) ? v : (__expf(v) - 1.f));
    // fp16 fragment-image index for (row=node, k=dbase..dbase+3)
    const int rtg = node >> 4;
    const int kb = dbase >> 5;
    const int li = (node & 15) + ((dbase >> 3) & 3) * 16;
    const size_t idx = ((size_t)rtg * 8 + kb) * 512 + li * 8 + (dbase & 7);
    *(half4v*)&h0img[idx] = o;
}

// ---------------- layer 1 edge kernel: packed score, no-max, 2-deep per group ----

__global__ __launch_bounds__(256) void gat_edge1(const _Float16* __restrict__ feat,
                                                 const float* __restrict__ attn,
                                                 const int* __restrict__ rowptr,
                                                 const int* __restrict__ csr,
                                                 float* __restrict__ out) {
    const int lane = threadIdx.x & 63;
    const int node = blockIdx.x * 4 + (threadIdx.x >> 6);
    if (node >= N_NODES) return;
    const int g = lane >> 4;
    const int d0 = (lane & 15) * 4;
    const float4 a = *(const float4*)&attn[d0];
    H4 A6, A4;
    A6.h4 = (half4v){(_Float16)(0.6f * LOG2E * a.x), (_Float16)(0.6f * LOG2E * a.y),
                     (_Float16)(0.6f * LOG2E * a.z), (_Float16)(0.6f * LOG2E * a.w)};
    A4.h4 = (half4v){(_Float16)(0.4f * LOG2E * a.x), (_Float16)(0.4f * LOG2E * a.y),
                     (_Float16)(0.4f * LOG2E * a.z), (_Float16)(0.4f * LOG2E * a.w)};
    const char* fbase = (const char*)feat + d0 * 2;
    const half4v fd4 = *(const half4v*)(fbase + ((size_t)node << 7));
    const int beg = rowptr[node], end = rowptr[node + 1];
    float s = 0.f, ax = 0.f, ay = 0.f, az = 0.f, aw = 0.f;
    int j = beg + g;
    for (; j + 4 < end; j += 8) {
        half4v g0 = *(const half4v*)(fbase + csr[j]);
        half4v g1 = *(const half4v*)(fbase + csr[j + 4]);
        float p0 = score4(g0, fd4, A6, A4);
        float p1 = score4(g1, fd4, A6, A4);
        p0 += __shfl_xor(p0, 1); p1 += __shfl_xor(p1, 1);
        p0 += __shfl_xor(p0, 2); p1 += __shfl_xor(p1, 2);
        p0 += __shfl_xor(p0, 4); p1 += __shfl_xor(p1, 4);
        p0 += __shfl_xor(p0, 8); p1 += __shfl_xor(p1, 8);
        float e0 = __builtin_amdgcn_exp2f(p0);
        float e1 = __builtin_amdgcn_exp2f(p1);
        s  += e0 + e1;
        ax += e0 * (float)g0[0] + e1 * (float)g1[0];
        ay += e0 * (float)g0[1] + e1 * (float)g1[1];
        az += e0 * (float)g0[2] + e1 * (float)g1[2];
        aw += e0 * (float)g0[3] + e1 * (float)g1[3];
    }
    if (j < end) {
        half4v g0 = *(const half4v*)(fbase + csr[j]);
        float p = score4(g0, fd4, A6, A4);
        p += __shfl_xor(p, 1);
        p += __shfl_xor(p, 2);
        p += __shfl_xor(p, 4);
        p += __shfl_xor(p, 8);
        float e = __builtin_amdgcn_exp2f(p);
        s  += e;
        ax += e * (float)g0[0];
        ay += e * (float)g0[1];
        az += e * (float)g0[2];
        aw += e * (float)g0[3];
    }
#pragma unroll
    for (int off = 16; off <= 32; off <<= 1) {
        s  += __shfl_xor(s, off);
        ax += __shfl_xor(ax, off);
        ay += __shfl_xor(ay, off);
        az += __shfl_xor(az, off);
        aw += __shfl_xor(aw, off);
    }
    if (g == 0) {
        float inv = (end > beg) ? (1.0f / s) : 0.f;
        float4 o = make_float4(ax * inv, ay * inv, az * inv, aw * inv);
        *(float4*)&out[(size_t)node * 64 + d0] = o;
    }
}

// ---------------- launch ----------------

extern "C" void kernel_launch(void* const* d_in, const int* in_sizes, int n_in,
                              void* d_out, int out_size, void* d_ws, size_t ws_size,
                              hipStream_t stream) {
    const float* x     = (const float*)d_in[0];
    const float* W0    = (const float*)d_in[1];
    const float* attn0 = (const float*)d_in[2];
    const float* W1    = (const float*)d_in[3];
    const float* attn1 = (const float*)d_in[4];
    const int*   src0  = (const int*)d_in[5];
    const int*   dst0  = (const int*)d_in[6];
    const int*   src1  = (const int*)d_in[7];
    const int*   dst1  = (const int*)d_in[8];
    float* out = (float*)d_out;

    _Float16* h0img  = (_Float16*)d_ws;                      // ROWS_PAD*256 (image)
    _Float16* feat0h = h0img + (size_t)ROWS_PAD * 256;       // N*256 fp16 (alias feat1h)
    _Float16* W0img  = feat0h + (size_t)N_NODES * 256;       // 256*256
    _Float16* W1img  = W0img + 256 * 256;                    // 64*256
    _Float16* feat1h = feat0h;

    int* deg_s    = (int*)(W1img + 64 * 256);
    int* rowptr   = deg_s + 2 * SLN;
    int* rowptr_s = rowptr + 2 * (N_NODES + 1);
    int* cursor_s = rowptr_s + 2 * SLN;
    int* bsum1    = cursor_s + 2 * SLN;
    int* boff1    = bsum1 + 512;
    int* bsum2    = boff1 + 512;
    int* boff2    = bsum2 + 2 * NB2;
    int* tmp      = boff2 + 2 * NB2;
    int* csr      = tmp + 2 * E_EDGES;

    const int eb = E_EDGES / 256;                  // 3125
    const int gb = ROWS_PAD / 64;                  // 782

    // ---- W images (one dispatch) ----
    k_wimg2<<<(256 * 32 + 64 * 32 + 255) / 256, 256, 0, stream>>>(W0, W1, W0img, W1img);

    // ---- CSR build (both layers) ----
    hipMemsetAsync(deg_s, 0, 2 * SLN * sizeof(int), stream);
    k_hist     <<<dim3(eb, 2),        256, 0, stream>>>(dst0, dst1, deg_s);
    k_scanA_all<<<dim3(NB1 + NB2, 2), 256, 0, stream>>>(deg_s, rowptr, bsum1, rowptr_s, bsum2);
    k_scanB_all<<<4,                  256, 0, stream>>>(bsum1, boff1, bsum2, boff2);
    k_scanC_all<<<dim3(NB2, 2),       256, 0, stream>>>(deg_s, boff1, boff2, rowptr, rowptr_s, cursor_s);
    k_scatter  <<<dim3(eb, 2),        256, 0, stream>>>(src0, dst0, src1, dst1, cursor_s, tmp);
    k_regroup  <<<dim3((N_NODES + 3) / 4, 2), 256, 0, stream>>>(deg_s, rowptr_s, rowptr, tmp, csr);

    // ---- layer 0 ----
    mfma_gemm4f<<<gb, 256, 0, stream>>>(x, W0img, feat0h, N_NODES);
    gat_edge0<<<(N_NODES + 3) / 4, 256, 0, stream>>>(feat0h, attn0, rowptr, csr, h0img);

    // ---- layer 1 ----
    mfma_gemm3f<64><<<gb, 256, 0, stream>>>(h0img, W1img, feat1h, N_NODES);
    gat_edge1<<<(N_NODES + 3) / 4, 256, 0, stream>>>(feat1h, attn1,
                                                     rowptr + (N_NODES + 1), csr + E_EDGES, out);
}

// Round 11
// 274.180 us; speedup vs baseline: 1.4861x; 1.1024x over previous
//
#include <hip/hip_runtime.h>

#define N_NODES 50000
#define E_EDGES 800000
#define NEG_SLOPE 0.2f
#define NSL 8
#define SLN (NSL * N_NODES)          // 400000
#define NB1 196                      // ceil(N/256)
#define NB2 1563                     // ceil(8N/256)
#define ROWS_PAD 50048               // N padded to 64
#define GB0 782                      // gemm blocks (ROWS_PAD/64)
#define EB 3125                      // edge blocks per layer (E/256)
#define NBE0 12500                   // edge0 node blocks (N/4)

typedef __attribute__((ext_vector_type(8))) _Float16 f16x8;
typedef __attribute__((ext_vector_type(4))) float f32x4;
typedef __attribute__((ext_vector_type(4))) _Float16 half4v;
typedef __attribute__((ext_vector_type(2))) _Float16 half2v;

union H4 { half4v h4; half2v h2[2]; unsigned u[2]; };

// async global->LDS DMA, 16B/lane; LDS dest = wave-uniform base + lane*16
__device__ __forceinline__ void gload_lds16(const void* g, void* l) {
    __builtin_amdgcn_global_load_lds((__attribute__((address_space(1))) void*)g,
                                     (__attribute__((address_space(3))) void*)l, 16, 0, 0);
}

#define LOG2E 1.4426950408889634f

// packed score: p_log2 = sum_d (0.6*log2e*a_d)*z_d + (0.4*log2e*a_d)*|z_d|
__device__ __forceinline__ float score4(half4v g, half4v fd, const H4& A6, const H4& A4) {
    H4 Z; Z.h4 = g + fd;
    H4 B; B.u[0] = Z.u[0] & 0x7FFF7FFFu; B.u[1] = Z.u[1] & 0x7FFF7FFFu;
    float p = __builtin_amdgcn_fdot2(Z.h2[0], A6.h2[0], 0.0f, false);
    p = __builtin_amdgcn_fdot2(Z.h2[1], A6.h2[1], p, false);
    p = __builtin_amdgcn_fdot2(B.h2[0], A4.h2[0], p, false);
    p = __builtin_amdgcn_fdot2(B.h2[1], A4.h2[1], p, false);
    return p;
}

// W fragment image: elem (col,k) -> img[(k/32)*CT*512 + (col/16)*512 + ((col&15)+((k>>3)&3)*16)*8 + (k&7)]
__device__ __forceinline__ void wimg_one(const float* W, _Float16* img, int Nc, int i) {
    int col = i >> 5, chunk = i & 31;
    int CT = Nc >> 4;
    int kb = chunk >> 2, ct = col >> 4;
    int li = (col & 15) + (chunk & 3) * 16;
    size_t base = ((size_t)kb * CT + ct) * 512 + li * 8;
    half4v v0, v1;
#pragma unroll
    for (int e = 0; e < 4; ++e) v0[e] = (_Float16)W[(size_t)(chunk * 8 + e) * Nc + col];
#pragma unroll
    for (int e = 0; e < 4; ++e) v1[e] = (_Float16)W[(size_t)(chunk * 8 + 4 + e) * Nc + col];
    *(half4v*)&img[base]     = v0;
    *(half4v*)&img[base + 4] = v1;
}

// ---------------- d1: W images + deg_s zero ----------------

__global__ void k_init(const float* __restrict__ W0, const float* __restrict__ W1,
                       _Float16* __restrict__ img0, _Float16* __restrict__ img1,
                       int* __restrict__ deg_s) {
    int gtid = blockIdx.x * 256 + threadIdx.x;
    if (gtid < 2 * SLN / 4) ((int4*)deg_s)[gtid] = make_int4(0, 0, 0, 0);
    if (gtid < 256 * 32) wimg_one(W0, img0, 256, gtid);
    else if (gtid < 256 * 32 + 64 * 32) wimg_one(W1, img1, 64, gtid - 256 * 32);
}

// ---------------- d2: gemm0 (fp16 MFMA, reg-staged A, image B) ∥ hist(both layers) ----

__global__ __launch_bounds__(256, 4) void k_gemm0_hist(const float* __restrict__ X,
                                                       const _Float16* __restrict__ Bimg,
                                                       _Float16* __restrict__ C, int M,
                                                       const int* __restrict__ dst0,
                                                       const int* __restrict__ dst1,
                                                       int* __restrict__ deg_s) {
    constexpr int CT = 16;
    __shared__ __align__(16) _Float16 AsF[4 * 512];
    __shared__ __align__(16) _Float16 Bs[CT * 512];

    if (blockIdx.x >= GB0) {
        // ---- hist role ----
        int hb = blockIdx.x - GB0;
        int layer = (hb >= EB) ? 1 : 0;
        int bi = hb - layer * EB;
        int slice = bi & (NSL - 1);
        int i = bi * 256 + threadIdx.x;
        int d = (layer == 0) ? dst0[i] : dst1[i];
        atomicAdd(&deg_s[layer * SLN + slice * N_NODES + d], 1);
        return;
    }

    const int t = threadIdx.x;
    const int w = t >> 6;
    const int lane = t & 63;
    const int r16 = lane & 15;
    const int kg = lane >> 4;
    const int bm = blockIdx.x * 64;
    const int arow = bm + w * 16 + r16;
    const bool rv = (arow < M);
    const float* xsrc = X + (size_t)arow * 256 + kg * 8;

    f32x4 acc[CT];
#pragma unroll
    for (int j = 0; j < CT; ++j) acc[j] = (f32x4){0.f, 0.f, 0.f, 0.f};

    for (int kb = 0; kb < 8; ++kb) {
        float4 v0 = make_float4(0.f, 0.f, 0.f, 0.f);
        float4 v1 = make_float4(0.f, 0.f, 0.f, 0.f);
        if (rv) {
            v0 = *(const float4*)(xsrc + kb * 32);
            v1 = *(const float4*)(xsrc + kb * 32 + 4);
        }
        f16x8 af;
        af[0] = (_Float16)v0.x; af[1] = (_Float16)v0.y;
        af[2] = (_Float16)v0.z; af[3] = (_Float16)v0.w;
        af[4] = (_Float16)v1.x; af[5] = (_Float16)v1.y;
        af[6] = (_Float16)v1.z; af[7] = (_Float16)v1.w;
        *(f16x8*)&AsF[t * 8] = af;
#pragma unroll
        for (int p = 0; p < CT / 4; ++p)
            gload_lds16(Bimg + kb * CT * 512 + p * 2048 + t * 8, &Bs[p * 2048 + w * 512]);
        __syncthreads();

        const f16x8 aF = *(const f16x8*)&AsF[t * 8];
#pragma unroll
        for (int ct = 0; ct < CT; ++ct) {
            const f16x8 b = *(const f16x8*)&Bs[ct * 512 + lane * 8];
            acc[ct] = __builtin_amdgcn_mfma_f32_16x16x32_f16(aF, b, acc[ct], 0, 0, 0);
        }
        __syncthreads();
    }

#pragma unroll
    for (int r = 0; r < 4; ++r) {
        int row = bm + w * 16 + kg * 4 + r;
        if (row < M) {
#pragma unroll
            for (int ct = 0; ct < CT; ++ct)
                C[(size_t)row * 256 + ct * 16 + r16] = (_Float16)acc[ct][r];
        }
    }
}

// ---------------- scans (both layers) ----------------

__global__ void k_scanA_all(const int* __restrict__ deg_s, int* __restrict__ rowptr,
                            int* __restrict__ bsum1, int* __restrict__ rowptr_s,
                            int* __restrict__ bsum2) {
    const int layer = blockIdx.y;
    __shared__ int lds[256];
    int t = threadIdx.x;
    if (blockIdx.x < NB1) {
        int i = blockIdx.x * 256 + t;
        int v = 0;
        if (i < N_NODES) {
            const int* d = deg_s + layer * SLN + i;
#pragma unroll
            for (int s = 0; s < NSL; ++s) v += d[s * N_NODES];
        }
        lds[t] = v;
        __syncthreads();
        for (int off = 1; off < 256; off <<= 1) {
            int u = (t >= off) ? lds[t - off] : 0;
            __syncthreads();
            lds[t] += u;
            __syncthreads();
        }
        if (i < N_NODES) rowptr[layer * (N_NODES + 1) + i + 1] = lds[t];
        if (t == 255) bsum1[layer * 256 + blockIdx.x] = lds[255];
    } else {
        int bx = blockIdx.x - NB1;
        int i = bx * 256 + t;
        int v = (i < SLN) ? deg_s[layer * SLN + i] : 0;
        lds[t] = v;
        __syncthreads();
        for (int off = 1; off < 256; off <<= 1) {
            int u = (t >= off) ? lds[t - off] : 0;
            __syncthreads();
            lds[t] += u;
            __syncthreads();
        }
        if (i < SLN) rowptr_s[layer * SLN + i] = lds[t];
        if (t == 255) bsum2[layer * NB2 + bx] = lds[255];
    }
}

__global__ void k_scanB_all(const int* __restrict__ bsum1, int* __restrict__ boff1,
                            const int* __restrict__ bsum2, int* __restrict__ boff2) {
    __shared__ int lds[256];
    __shared__ int carry;
    int t = threadIdx.x;
    if (blockIdx.x < 2) {
        const int layer = blockIdx.x;
        int v = (t < NB1) ? bsum1[layer * 256 + t] : 0;
        lds[t] = v;
        __syncthreads();
        for (int off = 1; off < 256; off <<= 1) {
            int u = (t >= off) ? lds[t - off] : 0;
            __syncthreads();
            lds[t] += u;
            __syncthreads();
        }
        if (t < NB1) boff1[layer * 256 + t] = lds[t] - v;
    } else {
        const int layer = blockIdx.x - 2;
        if (t == 0) carry = 0;
        __syncthreads();
        for (int c = 0; c < NB2; c += 256) {
            int v = (c + t < NB2) ? bsum2[layer * NB2 + c + t] : 0;
            lds[t] = v;
            __syncthreads();
            for (int off = 1; off < 256; off <<= 1) {
                int u = (t >= off) ? lds[t - off] : 0;
                __syncthreads();
                lds[t] += u;
                __syncthreads();
            }
            if (c + t < NB2) boff2[layer * NB2 + c + t] = carry + lds[t] - v;
            __syncthreads();
            if (t == 255) carry += lds[255];
            __syncthreads();
        }
    }
}

__global__ void k_scanC_all(const int* __restrict__ deg_s, const int* __restrict__ boff1,
                            const int* __restrict__ boff2, int* __restrict__ rowptr,
                            int* __restrict__ rowptr_s, int* __restrict__ cursor_s) {
    const int layer = blockIdx.y;
    int i = blockIdx.x * 256 + threadIdx.x;
    if (i < SLN) {
        const int base = layer * SLN;
        int b = rowptr_s[base + i] + boff2[layer * NB2 + (i >> 8)] - deg_s[base + i];
        rowptr_s[base + i] = b;
        cursor_s[base + i] = b;
    }
    if (i < N_NODES) {
        int* rp = rowptr + layer * (N_NODES + 1);
        rp[i + 1] += boff1[layer * 256 + (i >> 8)];
        if (i == 0) rp[0] = 0;
    }
}

// ---------------- layer-0 scatter / regroup ----------------

__global__ void k_scatter0(const int* __restrict__ src0, const int* __restrict__ dst0,
                           int* __restrict__ cursor_s, int* __restrict__ tmp) {
    const int slice = blockIdx.x & (NSL - 1);
    int i = blockIdx.x * 256 + threadIdx.x;
    int s = src0[i], d = dst0[i];
    int pos = atomicAdd(&cursor_s[slice * N_NODES + d], 1);
    tmp[pos] = s;
}

// regroup body: writes csr as BYTE offsets (<<sh)
__device__ __forceinline__ void regroup_node(const int* __restrict__ deg_s,
                                             const int* __restrict__ rowptr_s,
                                             const int* __restrict__ rowptr,
                                             const int* __restrict__ tmp,
                                             int* __restrict__ csr,
                                             int layer, int node, int lane, int sh) {
    const int base = layer * SLN;
    int dg = 0, tb = 0;
    if (lane < NSL) {
        dg = deg_s[base + lane * N_NODES + node];
        tb = rowptr_s[base + lane * N_NODES + node];
    }
    int excl = 0, total = 0;
#pragma unroll
    for (int ss = 0; ss < NSL; ++ss) {
        int v = __shfl(dg, ss);
        if (ss < (lane & 7)) excl += v;
        total += v;
    }
    const int base_out = rowptr[layer * (N_NODES + 1) + node];
    const int* tsrc = tmp + (size_t)layer * E_EDGES;
    int* cdst = csr + (size_t)layer * E_EDGES;
    for (int r0 = 0; r0 < total; r0 += 64) {
        int r = r0 + lane;
        bool active = (r < total);
        int rr = active ? r : 0;
        int s = 0;
#pragma unroll
        for (int ss = 1; ss < NSL; ++ss) {
            int e = __shfl(excl, ss);
            if (rr >= e) s = ss;
        }
        int eS  = __shfl(excl, s);
        int tbS = __shfl(tb, s);
        if (active) cdst[base_out + r] = tsrc[tbS + (r - eS)] << sh;
    }
}

__global__ __launch_bounds__(256) void k_regroup0(const int* __restrict__ deg_s,
                                                  const int* __restrict__ rowptr_s,
                                                  const int* __restrict__ rowptr,
                                                  const int* __restrict__ tmp,
                                                  int* __restrict__ csr) {
    const int lane = threadIdx.x & 63;
    const int node = blockIdx.x * 4 + (threadIdx.x >> 6);
    if (node >= N_NODES) return;
    regroup_node(deg_s, rowptr_s, rowptr, tmp, csr, 0, node, lane, 9);
}

// ---------------- d8: edge0 ∥ scatter1 ----------------

__global__ __launch_bounds__(256) void k_edge0_scatter1(const _Float16* __restrict__ feat,
                                                        const float* __restrict__ attn,
                                                        const int* __restrict__ rowptr,
                                                        const int* __restrict__ csr,
                                                        _Float16* __restrict__ h0img,
                                                        const int* __restrict__ src1,
                                                        const int* __restrict__ dst1,
                                                        int* __restrict__ cursor_s,
                                                        int* __restrict__ tmp) {
    if (blockIdx.x >= NBE0) {
        // ---- scatter1 role ----
        int bi = blockIdx.x - NBE0;
        const int slice = bi & (NSL - 1);
        int i = bi * 256 + threadIdx.x;
        int s = src1[i], d = dst1[i];
        int pos = atomicAdd(&cursor_s[SLN + slice * N_NODES + d], 1);
        tmp[E_EDGES + pos] = s;
        return;
    }
    const int lane = threadIdx.x & 63;
    const int node = blockIdx.x * 4 + (threadIdx.x >> 6);
    if (node >= N_NODES) return;
    const int dbase = ((lane >> 4) << 6) + (lane & 15) * 4;
    const float4 a = *(const float4*)&attn[dbase];
    H4 A6, A4;
    A6.h4 = (half4v){(_Float16)(0.6f * LOG2E * a.x), (_Float16)(0.6f * LOG2E * a.y),
                     (_Float16)(0.6f * LOG2E * a.z), (_Float16)(0.6f * LOG2E * a.w)};
    A4.h4 = (half4v){(_Float16)(0.4f * LOG2E * a.x), (_Float16)(0.4f * LOG2E * a.y),
                     (_Float16)(0.4f * LOG2E * a.z), (_Float16)(0.4f * LOG2E * a.w)};
    const char* fbase = (const char*)feat + dbase * 2;
    const half4v fd4 = *(const half4v*)(fbase + ((size_t)node << 9));
    const int beg = rowptr[node], end = rowptr[node + 1];
    float s = 0.f, ax = 0.f, ay = 0.f, az = 0.f, aw = 0.f;
    int j = beg;
    for (; j + 7 < end; j += 8) {
        half4v g[8];
        float p[8];
#pragma unroll
        for (int i = 0; i < 8; ++i) g[i] = *(const half4v*)(fbase + csr[j + i]);
#pragma unroll
        for (int i = 0; i < 8; ++i) p[i] = score4(g[i], fd4, A6, A4);
#pragma unroll
        for (int r = 1; r <= 8; r <<= 1)
#pragma unroll
            for (int i = 0; i < 8; ++i) p[i] += __shfl_xor(p[i], r);
        float e[8];
#pragma unroll
        for (int i = 0; i < 8; ++i) e[i] = __builtin_amdgcn_exp2f(p[i]);
#pragma unroll
        for (int i = 0; i < 8; ++i) {
            s  += e[i];
            ax += e[i] * (float)g[i][0];
            ay += e[i] * (float)g[i][1];
            az += e[i] * (float)g[i][2];
            aw += e[i] * (float)g[i][3];
        }
    }
    if (j + 3 < end) {
        half4v g[4];
        float p[4];
#pragma unroll
        for (int i = 0; i < 4; ++i) g[i] = *(const half4v*)(fbase + csr[j + i]);
#pragma unroll
        for (int i = 0; i < 4; ++i) p[i] = score4(g[i], fd4, A6, A4);
#pragma unroll
        for (int r = 1; r <= 8; r <<= 1)
#pragma unroll
            for (int i = 0; i < 4; ++i) p[i] += __shfl_xor(p[i], r);
#pragma unroll
        for (int i = 0; i < 4; ++i) {
            float e = __builtin_amdgcn_exp2f(p[i]);
            s  += e;
            ax += e * (float)g[i][0];
            ay += e * (float)g[i][1];
            az += e * (float)g[i][2];
            aw += e * (float)g[i][3];
        }
        j += 4;
    }
    for (; j < end; ++j) {
        half4v g0 = *(const half4v*)(fbase + csr[j]);
        float p0 = score4(g0, fd4, A6, A4);
        p0 += __shfl_xor(p0, 1);
        p0 += __shfl_xor(p0, 2);
        p0 += __shfl_xor(p0, 4);
        p0 += __shfl_xor(p0, 8);
        float e0 = __builtin_amdgcn_exp2f(p0);
        s  += e0;
        ax += e0 * (float)g0[0];
        ay += e0 * (float)g0[1];
        az += e0 * (float)g0[2];
        aw += e0 * (float)g0[3];
    }
    float inv = (end > beg) ? (1.0f / s) : 0.f;
    half4v o;
    float v;
    v = ax * inv; o[0] = (_Float16)((v > 0.f) ? v : (__expf(v) - 1.f));
    v = ay * inv; o[1] = (_Float16)((v > 0.f) ? v : (__expf(v) - 1.f));
    v = az * inv; o[2] = (_Float16)((v > 0.f) ? v : (__expf(v) - 1.f));
    v = aw * inv; o[3] = (_Float16)((v > 0.f) ? v : (__expf(v) - 1.f));
    const int rtg = node >> 4;
    const int kb = dbase >> 5;
    const int li = (node & 15) + ((dbase >> 3) & 3) * 16;
    const size_t idx = ((size_t)rtg * 8 + kb) * 512 + li * 8 + (dbase & 7);
    *(half4v*)&h0img[idx] = o;
}

// ---------------- d9: gemm1 (fp16 image A+B) ∥ regroup1 ----------------

__global__ __launch_bounds__(256, 4) void k_gemm1_regroup1(const _Float16* __restrict__ Aimg,
                                                           const _Float16* __restrict__ Bimg,
                                                           _Float16* __restrict__ C, int M,
                                                           const int* __restrict__ deg_s,
                                                           const int* __restrict__ rowptr_s,
                                                           const int* __restrict__ rowptr,
                                                           const int* __restrict__ tmp,
                                                           int* __restrict__ csr) {
    constexpr int CT = 4;   // BN = 64
    __shared__ __align__(16) _Float16 AsF[4 * 512];
    __shared__ __align__(16) _Float16 Bs[CT * 512];

    if (blockIdx.x >= GB0) {
        // ---- regroup1 role ----
        const int lane = threadIdx.x & 63;
        const int node = (blockIdx.x - GB0) * 4 + (threadIdx.x >> 6);
        if (node >= N_NODES) return;
        regroup_node(deg_s, rowptr_s, rowptr, tmp, csr, 1, node, lane, 7);
        return;
    }

    const int t = threadIdx.x;
    const int w = t >> 6;
    const int lane = t & 63;
    const int r16 = lane & 15;
    const int kg = lane >> 4;
    const int bm = blockIdx.x * 64;

    f32x4 acc[CT];
#pragma unroll
    for (int j = 0; j < CT; ++j) acc[j] = (f32x4){0.f, 0.f, 0.f, 0.f};

    const size_t abase = ((size_t)(blockIdx.x * 4 + w)) * 8 * 512;

    for (int kb = 0; kb < 8; ++kb) {
        gload_lds16(Aimg + abase + kb * 512 + lane * 8, &AsF[w * 512]);
        gload_lds16(Bimg + kb * CT * 512 + t * 8, &Bs[w * 512]);
        __syncthreads();

        const f16x8 aF = *(const f16x8*)&AsF[w * 512 + lane * 8];
#pragma unroll
        for (int ct = 0; ct < CT; ++ct) {
            const f16x8 b = *(const f16x8*)&Bs[ct * 512 + lane * 8];
            acc[ct] = __builtin_amdgcn_mfma_f32_16x16x32_f16(aF, b, acc[ct], 0, 0, 0);
        }
        __syncthreads();
    }

#pragma unroll
    for (int r = 0; r < 4; ++r) {
        int row = bm + w * 16 + kg * 4 + r;
        if (row < M) {
#pragma unroll
            for (int ct = 0; ct < CT; ++ct)
                C[(size_t)row * 64 + ct * 16 + r16] = (_Float16)acc[ct][r];
        }
    }
}

// ---------------- layer 1 edge kernel ----------------

__global__ __launch_bounds__(256) void gat_edge1(const _Float16* __restrict__ feat,
                                                 const float* __restrict__ attn,
                                                 const int* __restrict__ rowptr,
                                                 const int* __restrict__ csr,
                                                 float* __restrict__ out) {
    const int lane = threadIdx.x & 63;
    const int node = blockIdx.x * 4 + (threadIdx.x >> 6);
    if (node >= N_NODES) return;
    const int g = lane >> 4;
    const int d0 = (lane & 15) * 4;
    const float4 a = *(const float4*)&attn[d0];
    H4 A6, A4;
    A6.h4 = (half4v){(_Float16)(0.6f * LOG2E * a.x), (_Float16)(0.6f * LOG2E * a.y),
                     (_Float16)(0.6f * LOG2E * a.z), (_Float16)(0.6f * LOG2E * a.w)};
    A4.h4 = (half4v){(_Float16)(0.4f * LOG2E * a.x), (_Float16)(0.4f * LOG2E * a.y),
                     (_Float16)(0.4f * LOG2E * a.z), (_Float16)(0.4f * LOG2E * a.w)};
    const char* fbase = (const char*)feat + d0 * 2;
    const half4v fd4 = *(const half4v*)(fbase + ((size_t)node << 7));
    const int beg = rowptr[node], end = rowptr[node + 1];
    float s = 0.f, ax = 0.f, ay = 0.f, az = 0.f, aw = 0.f;
    int j = beg + g;
    for (; j + 4 < end; j += 8) {
        half4v g0 = *(const half4v*)(fbase + csr[j]);
        half4v g1 = *(const half4v*)(fbase + csr[j + 4]);
        float p0 = score4(g0, fd4, A6, A4);
        float p1 = score4(g1, fd4, A6, A4);
        p0 += __shfl_xor(p0, 1); p1 += __shfl_xor(p1, 1);
        p0 += __shfl_xor(p0, 2); p1 += __shfl_xor(p1, 2);
        p0 += __shfl_xor(p0, 4); p1 += __shfl_xor(p1, 4);
        p0 += __shfl_xor(p0, 8); p1 += __shfl_xor(p1, 8);
        float e0 = __builtin_amdgcn_exp2f(p0);
        float e1 = __builtin_amdgcn_exp2f(p1);
        s  += e0 + e1;
        ax += e0 * (float)g0[0] + e1 * (float)g1[0];
        ay += e0 * (float)g0[1] + e1 * (float)g1[1];
        az += e0 * (float)g0[2] + e1 * (float)g1[2];
        aw += e0 * (float)g0[3] + e1 * (float)g1[3];
    }
    if (j < end) {
        half4v g0 = *(const half4v*)(fbase + csr[j]);
        float p = score4(g0, fd4, A6, A4);
        p += __shfl_xor(p, 1);
        p += __shfl_xor(p, 2);
        p += __shfl_xor(p, 4);
        p += __shfl_xor(p, 8);
        float e = __builtin_amdgcn_exp2f(p);
        s  += e;
        ax += e * (float)g0[0];
        ay += e * (float)g0[1];
        az += e * (float)g0[2];
        aw += e * (float)g0[3];
    }
#pragma unroll
    for (int off = 16; off <= 32; off <<= 1) {
        s  += __shfl_xor(s, off);
        ax += __shfl_xor(ax, off);
        ay += __shfl_xor(ay, off);
        az += __shfl_xor(az, off);
        aw += __shfl_xor(aw, off);
    }
    if (g == 0) {
        float inv = (end > beg) ? (1.0f / s) : 0.f;
        float4 o = make_float4(ax * inv, ay * inv, az * inv, aw * inv);
        *(float4*)&out[(size_t)node * 64 + d0] = o;
    }
}

// ---------------- launch ----------------

extern "C" void kernel_launch(void* const* d_in, const int* in_sizes, int n_in,
                              void* d_out, int out_size, void* d_ws, size_t ws_size,
                              hipStream_t stream) {
    const float* x     = (const float*)d_in[0];
    const float* W0    = (const float*)d_in[1];
    const float* attn0 = (const float*)d_in[2];
    const float* W1    = (const float*)d_in[3];
    const float* attn1 = (const float*)d_in[4];
    const int*   src0  = (const int*)d_in[5];
    const int*   dst0  = (const int*)d_in[6];
    const int*   src1  = (const int*)d_in[7];
    const int*   dst1  = (const int*)d_in[8];
    float* out = (float*)d_out;

    _Float16* h0img  = (_Float16*)d_ws;                      // ROWS_PAD*256 (image)
    _Float16* feat0h = h0img + (size_t)ROWS_PAD * 256;       // N*256 fp16 (alias feat1h)
    _Float16* W0img  = feat0h + (size_t)N_NODES * 256;       // 256*256
    _Float16* W1img  = W0img + 256 * 256;                    // 64*256
    _Float16* feat1h = feat0h;

    int* deg_s    = (int*)(W1img + 64 * 256);
    int* rowptr   = deg_s + 2 * SLN;
    int* rowptr_s = rowptr + 2 * (N_NODES + 1);
    int* cursor_s = rowptr_s + 2 * SLN;
    int* bsum1    = cursor_s + 2 * SLN;
    int* boff1    = bsum1 + 512;
    int* bsum2    = boff1 + 512;
    int* boff2    = bsum2 + 2 * NB2;
    int* tmp      = boff2 + 2 * NB2;
    int* csr      = tmp + 2 * E_EDGES;

    // d1: W images + zero deg_s
    k_init<<<GB0, 256, 0, stream>>>(W0, W1, W0img, W1img, deg_s);

    // d2: gemm0 ∥ hist(both layers)
    k_gemm0_hist<<<GB0 + 2 * EB, 256, 0, stream>>>(x, W0img, feat0h, N_NODES, dst0, dst1, deg_s);

    // d3-d5: scans (both layers)
    k_scanA_all<<<dim3(NB1 + NB2, 2), 256, 0, stream>>>(deg_s, rowptr, bsum1, rowptr_s, bsum2);
    k_scanB_all<<<4,                  256, 0, stream>>>(bsum1, boff1, bsum2, boff2);
    k_scanC_all<<<dim3(NB2, 2),       256, 0, stream>>>(deg_s, boff1, boff2, rowptr, rowptr_s, cursor_s);

    // d6-d7: layer-0 scatter + regroup
    k_scatter0<<<EB, 256, 0, stream>>>(src0, dst0, cursor_s, tmp);
    k_regroup0<<<(N_NODES + 3) / 4, 256, 0, stream>>>(deg_s, rowptr_s, rowptr, tmp, csr);

    // d8: edge0 ∥ scatter1
    k_edge0_scatter1<<<NBE0 + EB, 256, 0, stream>>>(feat0h, attn0, rowptr, csr, h0img,
                                                    src1, dst1, cursor_s, tmp);

    // d9: gemm1 ∥ regroup1
    k_gemm1_regroup1<<<GB0 + NBE0, 256, 0, stream>>>(h0img, W1img, feat1h, N_NODES,
                                                     deg_s, rowptr_s, rowptr, tmp, csr);

    // d10: edge1
    gat_edge1<<<NBE0, 256, 0, stream>>>(feat1h, attn1, rowptr + (N_NODES + 1),
                                        csr + E_EDGES, out);
}